// Round 9
// baseline (1247.070 us; speedup 1.0000x reference)
//
#include <hip/hip_runtime.h>

#define NROWS 8192
#define V 20
#define C 128
#define T 64
#define HDIM 192
#define DEPTH 3

typedef __attribute__((ext_vector_type(8))) short bf16x8;
typedef __attribute__((ext_vector_type(4))) float floatx4;

// ---- ws segment offsets (bf16 elements), all W^T [N][K] ----
#define WS_TOKFC1 0        // [64][32]  (k>=20 zero-padded)
#define WS_TOKFC2 2048     // [64][64]
#define WS_BTOK1  6144     // [3][64][64]
#define WS_BTOK2  18432    // [3][64][64]
#define WS_CHFC2  30720    // [128][128]
#define WS_BCH1   47104    // [3][128][128]
#define WS_BCH2   96256    // [3][128][128]
#define WS_TOTAL  145408   // elements -> 290816 bytes

// ---------- helpers ----------
__device__ __forceinline__ float bf2f(unsigned short u) {
    union { unsigned int i; float f; } c; c.i = ((unsigned int)u) << 16; return c.f;
}
__device__ __forceinline__ unsigned short f2bf(float f) {
    union { float f; unsigned int i; } c; c.f = f;
    unsigned int r = c.i + 0x7fffu + ((c.i >> 16) & 1u);  // RNE
    return (unsigned short)(r >> 16);
}
// Fast GELU (tanh form): x * sigmoid(1.59576912*(x + 0.044715 x^3)).
__device__ __forceinline__ float gelu(float x) {
    float u = x * x;
    float p = fmaf(u, 0.044715f, 1.0f);
    float arg = x * p * -2.3022042f;   // -1.59576912 * log2(e)
    float e = __builtin_amdgcn_exp2f(arg);
    return x * __builtin_amdgcn_rcpf(1.0f + e);
}
__device__ __forceinline__ floatx4 mfma16(bf16x8 a, bf16x8 b, floatx4 c) {
    return __builtin_amdgcn_mfma_f32_16x16x32_bf16(a, b, c, 0, 0, 0);
}

// ============ 2-rows-per-block building blocks ============
// Block = 256 threads = 4 waves; waves {0,1} -> row 0, waves {2,3} -> row 1.
// Within a row: vw = wid&1. Thread owns tokens t = 32*vw + 16*mt + rrow + rr
// (mt in {0,1}) x channels c = 16*nt + lrow -> R[2][8] floatx4 (64 fp32).
// Both fc2 GEMMs are oriented so MFMA C/D layout == R layout (seeded C-in).

// LayerNorm from registers; writes normalized bf16 to this row's s1 region.
__device__ __forceinline__ void ln_reg2(const floatx4 (&R)[2][8],
                                        const float* __restrict__ w,
                                        const float* __restrict__ b,
                                        unsigned short* __restrict__ s1r,
                                        int vw, int lrow, int rrow, bool transposed)
{
#pragma unroll
    for (int mt = 0; mt < 2; ++mt) {
        float s[4], q[4];
#pragma unroll
        for (int rr = 0; rr < 4; ++rr) {
            float ss = 0.f, qq = 0.f;
#pragma unroll
            for (int nt = 0; nt < 8; ++nt) { float v = R[mt][nt][rr]; ss += v; qq += v * v; }
            s[rr] = ss; q[rr] = qq;
        }
#pragma unroll
        for (int rr = 0; rr < 4; ++rr) {
            s[rr] += __shfl_xor(s[rr], 1);  q[rr] += __shfl_xor(q[rr], 1);
            s[rr] += __shfl_xor(s[rr], 2);  q[rr] += __shfl_xor(q[rr], 2);
            s[rr] += __shfl_xor(s[rr], 4);  q[rr] += __shfl_xor(q[rr], 4);
            s[rr] += __shfl_xor(s[rr], 8);  q[rr] += __shfl_xor(q[rr], 8);
        }
        float m[4], rs[4];
#pragma unroll
        for (int rr = 0; rr < 4; ++rr) {
            m[rr] = s[rr] * (1.f / 128.f);
            rs[rr] = rsqrtf(q[rr] * (1.f / 128.f) - m[rr] * m[rr] + 1e-5f);
        }
#pragma unroll
        for (int nt = 0; nt < 8; ++nt) {
            const int c = 16 * nt + lrow;
            const float wv = w[c], bv = b[c];
#pragma unroll
            for (int rr = 0; rr < 4; ++rr) {
                const int t = 32 * vw + 16 * mt + rrow + rr;
                unsigned short o = f2bf((R[mt][nt][rr] - m[rr]) * rs[rr] * wv + bv);
                if (transposed) s1r[c * 72 + t] = o;
                else            s1r[t * 136 + c] = o;
            }
        }
    }
}

// token fc1 (K=64): A = s1r [c][t], wave covers c-rows [64vw, 64vw+64) in 4
// mt chunks; gelu, in-place (read-then-write per chunk). Weights hoisted.
__device__ __forceinline__ void tok_fc1_g2(unsigned short* __restrict__ s1r,
                                           const unsigned short* __restrict__ wB,
                                           const float* __restrict__ bias,
                                           int vw, int lrow, int kq, int rrow)
{
    bf16x8 bw[4][2];
#pragma unroll
    for (int nt = 0; nt < 4; ++nt)
#pragma unroll
        for (int kc = 0; kc < 2; ++kc)
            bw[nt][kc] = *(const bf16x8*)(wB + (nt * 16 + lrow) * 64 + kc * 32 + kq);
#pragma unroll 1
    for (int mt = 0; mt < 4; ++mt) {
        const int m = 64 * vw + 16 * mt + lrow;
        bf16x8 af0 = *(const bf16x8*)(s1r + m * 72 + kq);
        bf16x8 af1 = *(const bf16x8*)(s1r + m * 72 + 32 + kq);
        floatx4 acc[4];
#pragma unroll
        for (int nt = 0; nt < 4; ++nt) acc[nt] = {0.f, 0.f, 0.f, 0.f};
#pragma unroll
        for (int nt = 0; nt < 4; ++nt) {
            acc[nt] = mfma16(af0, bw[nt][0], acc[nt]);
            acc[nt] = mfma16(af1, bw[nt][1], acc[nt]);
        }
#pragma unroll
        for (int nt = 0; nt < 4; ++nt) {
            const int t = nt * 16 + lrow;
            const float bb = bias[t];
#pragma unroll
            for (int rr = 0; rr < 4; ++rr)
                s1r[(64 * vw + 16 * mt + rrow + rr) * 72 + t] = f2bf(gelu(acc[nt][rr] + bb));
        }
    }
}

// token fc2 (K=64), operand-swapped: D[t'][c], wave owns t' in [32vw,32vw+32)
// (2 m-tiles). R is the seeded accumulator. Cross-wave reads: barrier around.
__device__ __forceinline__ void tok_fc2_R2(const unsigned short* __restrict__ s1r,
                                           const unsigned short* __restrict__ wB,
                                           const float* __restrict__ bias,
                                           floatx4 (&R)[2][8],
                                           int vw, int lrow, int kq, int rrow)
{
    bf16x8 aw[2][2];
#pragma unroll
    for (int mt = 0; mt < 2; ++mt)
#pragma unroll
        for (int kc = 0; kc < 2; ++kc)
            aw[mt][kc] = *(const bf16x8*)(wB + (32 * vw + 16 * mt + lrow) * 64 + kc * 32 + kq);
    float bb[2][4];
#pragma unroll
    for (int mt = 0; mt < 2; ++mt)
#pragma unroll
        for (int rr = 0; rr < 4; ++rr) bb[mt][rr] = bias[32 * vw + 16 * mt + rrow + rr];
#pragma unroll
    for (int nt = 0; nt < 8; ++nt) {
        bf16x8 b0 = *(const bf16x8*)(s1r + (16 * nt + lrow) * 72 + kq);
        bf16x8 b1 = *(const bf16x8*)(s1r + (16 * nt + lrow) * 72 + 32 + kq);
#pragma unroll
        for (int mt = 0; mt < 2; ++mt) {
            floatx4 acc = R[mt][nt];
            acc = mfma16(aw[mt][0], b0, acc);
            acc = mfma16(aw[mt][1], b1, acc);
#pragma unroll
            for (int rr = 0; rr < 4; ++rr) acc[rr] += bb[mt][rr];
            R[mt][nt] = acc;
        }
    }
}

// channel fc1 (K=128): wave owns t-rows [32vw,32vw+32) (2 m-tiles). A-frags
// for both tiles read ONCE up front (in-place safety: g>0 must not re-read
// columns overwritten by g=0). gelu, in-place.
__device__ __forceinline__ void ch_fc1_g2(unsigned short* __restrict__ s1r,
                                          const unsigned short* __restrict__ wB,
                                          const float* __restrict__ bias,
                                          int vw, int lrow, int kq, int rrow)
{
    bf16x8 a2[2][4];
#pragma unroll
    for (int mt = 0; mt < 2; ++mt) {
        const int m = 32 * vw + 16 * mt + lrow;
#pragma unroll
        for (int kc = 0; kc < 4; ++kc)
            a2[mt][kc] = *(const bf16x8*)(s1r + m * 136 + kc * 32 + kq);
    }
#pragma unroll 1
    for (int g = 0; g < 4; ++g) {
        bf16x8 bw[2][4];
#pragma unroll
        for (int i = 0; i < 2; ++i)
#pragma unroll
            for (int kc = 0; kc < 4; ++kc)
                bw[i][kc] = *(const bf16x8*)(wB + ((2 * g + i) * 16 + lrow) * 128 + kc * 32 + kq);
#pragma unroll
        for (int mt = 0; mt < 2; ++mt) {
            floatx4 acc[2];
#pragma unroll
            for (int i = 0; i < 2; ++i) acc[i] = {0.f, 0.f, 0.f, 0.f};
#pragma unroll
            for (int i = 0; i < 2; ++i)
#pragma unroll
                for (int kc = 0; kc < 4; ++kc)
                    acc[i] = mfma16(a2[mt][kc], bw[i][kc], acc[i]);
#pragma unroll
            for (int i = 0; i < 2; ++i) {
                const int c = (2 * g + i) * 16 + lrow;
                const float bb = bias[c];
#pragma unroll
                for (int rr = 0; rr < 4; ++rr)
                    s1r[(32 * vw + 16 * mt + rrow + rr) * 136 + c] = f2bf(gelu(acc[i][rr] + bb));
            }
        }
    }
}

// channel fc2 (K=128): R seeded accumulator; wave-local reads.
__device__ __forceinline__ void ch_fc2_R2(const unsigned short* __restrict__ s1r,
                                          const unsigned short* __restrict__ wB,
                                          const float* __restrict__ bias,
                                          floatx4 (&R)[2][8],
                                          int vw, int lrow, int kq, int rrow)
{
    bf16x8 a2[2][4];
#pragma unroll
    for (int mt = 0; mt < 2; ++mt) {
        const int m = 32 * vw + 16 * mt + lrow;
#pragma unroll
        for (int kc = 0; kc < 4; ++kc)
            a2[mt][kc] = *(const bf16x8*)(s1r + m * 136 + kc * 32 + kq);
    }
#pragma unroll 1
    for (int nt = 0; nt < 8; ++nt) {
        bf16x8 bw[4];
#pragma unroll
        for (int kc = 0; kc < 4; ++kc)
            bw[kc] = *(const bf16x8*)(wB + (16 * nt + lrow) * 128 + kc * 32 + kq);
        const float bb = bias[16 * nt + lrow];
#pragma unroll
        for (int mt = 0; mt < 2; ++mt) {
            floatx4 acc = R[mt][nt];
#pragma unroll
            for (int kc = 0; kc < 4; ++kc)
                acc = mfma16(a2[mt][kc], bw[kc], acc);
#pragma unroll
            for (int rr = 0; rr < 4; ++rr) acc[rr] += bb;
            R[mt][nt] = acc;
        }
    }
}

// LN over C=128 per token; 4 threads/token (scalar-fallback kernel only).
__device__ __forceinline__ void layer_norm_to(const float* __restrict__ sF,
                                              unsigned short* __restrict__ sA,
                                              const float* __restrict__ w,
                                              const float* __restrict__ b,
                                              int tid, bool transposed, int strideOut)
{
    const int t = tid >> 2, part = tid & 3;
    const float* row = sF + t * 132 + part * 32;
    float s = 0.f, q = 0.f;
#pragma unroll
    for (int j = 0; j < 8; ++j) {
        float4 v = *(const float4*)(row + j * 4);
        s += (v.x + v.y) + (v.z + v.w);
        q += v.x * v.x + v.y * v.y + v.z * v.z + v.w * v.w;
    }
    s += __shfl_xor(s, 1); q += __shfl_xor(q, 1);
    s += __shfl_xor(s, 2); q += __shfl_xor(q, 2);
    const float m = s * (1.f / 128.f);
    const float rs = rsqrtf(q * (1.f / 128.f) - m * m + 1e-5f);
#pragma unroll
    for (int j = 0; j < 8; ++j) {
        float4 v = *(const float4*)(row + j * 4);
        const int c = part * 32 + j * 4;
        float4 wv = *(const float4*)(w + c);
        float4 bv = *(const float4*)(b + c);
        unsigned short o0 = f2bf((v.x - m) * rs * wv.x + bv.x);
        unsigned short o1 = f2bf((v.y - m) * rs * wv.y + bv.y);
        unsigned short o2 = f2bf((v.z - m) * rs * wv.z + bv.z);
        unsigned short o3 = f2bf((v.w - m) * rs * wv.w + bv.w);
        if (transposed) {
            sA[(c + 0) * strideOut + t] = o0;
            sA[(c + 1) * strideOut + t] = o1;
            sA[(c + 2) * strideOut + t] = o2;
            sA[(c + 3) * strideOut + t] = o3;
        } else {
            ushort4 pk; pk.x = o0; pk.y = o1; pk.z = o2; pk.w = o3;
            *(ushort4*)(sA + t * strideOut + c) = pk;
        }
    }
}

// ---------- prep: fp32 [K][N] -> bf16 W^T [N][K] in ws ----------
__global__ void prep_weights(const float* __restrict__ tokfc1,
                             const float* __restrict__ tokfc2,
                             const float* __restrict__ btok1,
                             const float* __restrict__ btok2,
                             const float* __restrict__ chfc2,
                             const float* __restrict__ bch1,
                             const float* __restrict__ bch2,
                             unsigned short* __restrict__ ws)
{
    int idx = blockIdx.x * 256 + threadIdx.x;
    if (idx >= WS_TOTAL) return;
    if (idx < 2048) {                                   // tokfc1T [64][32]
        int n = idx >> 5, k = idx & 31;
        ws[WS_TOKFC1 + idx] = (k < V) ? f2bf(tokfc1[k * 64 + n]) : 0;
        return;
    }
    idx -= 2048;
    if (idx < 4096) {                                   // tokfc2T [64][64]
        int n = idx >> 6, k = idx & 63;
        ws[WS_TOKFC2 + idx] = f2bf(tokfc2[k * 64 + n]);
        return;
    }
    idx -= 4096;
    if (idx < 12288) {                                  // btok1T [3][64][64]
        int d = idx >> 12, rem = idx & 4095, n = rem >> 6, k = rem & 63;
        ws[WS_BTOK1 + idx] = f2bf(btok1[d * 4096 + k * 64 + n]);
        return;
    }
    idx -= 12288;
    if (idx < 12288) {                                  // btok2T [3][64][64]
        int d = idx >> 12, rem = idx & 4095, n = rem >> 6, k = rem & 63;
        ws[WS_BTOK2 + idx] = f2bf(btok2[d * 4096 + k * 64 + n]);
        return;
    }
    idx -= 12288;
    if (idx < 16384) {                                  // chfc2T [128][128]
        int n = idx >> 7, k = idx & 127;
        ws[WS_CHFC2 + idx] = f2bf(chfc2[k * 128 + n]);
        return;
    }
    idx -= 16384;
    if (idx < 49152) {                                  // bch1T [3][128][128]
        int d = idx >> 14, rem = idx & 16383, n = rem >> 7, k = rem & 127;
        ws[WS_BCH1 + idx] = f2bf(bch1[d * 16384 + k * 128 + n]);
        return;
    }
    idx -= 49152;
    {                                                   // bch2T [3][128][128]
        int d = idx >> 14, rem = idx & 16383, n = rem >> 7, k = rem & 127;
        ws[WS_BCH2 + idx] = f2bf(bch2[d * 16384 + k * 128 + n]);
    }
}

// ---------- MFMA main kernel: 2 rows per block (2 waves per row) ----------
__global__ __launch_bounds__(256) __attribute__((amdgpu_waves_per_eu(3)))
void lanefusion_mfma(
    const float* __restrict__ x,
    const float* __restrict__ tl_table, const float* __restrict__ lane_table,
    const float* __restrict__ ch_fc1_w, const float* __restrict__ ch_fc1_b,
    const float* __restrict__ ch_fc2_b,
    const float* __restrict__ tok_fc1_b, const float* __restrict__ tok_fc2_b,
    const float* __restrict__ bn1w, const float* __restrict__ bn1b,
    const float* __restrict__ btok1b, const float* __restrict__ btok2b,
    const float* __restrict__ bn2w, const float* __restrict__ bn2b,
    const float* __restrict__ bch1b, const float* __restrict__ bch2b,
    const float* __restrict__ norm_w, const float* __restrict__ norm_b,
    const float* __restrict__ emb1w, const float* __restrict__ emb1b,
    const float* __restrict__ emb2w, const float* __restrict__ emb2b,
    const unsigned short* __restrict__ ws,
    float* __restrict__ out)
{
    // Two 9216-short row regions. Per row: bf16 [128][72] token staging /
    // bf16 [64][136] channel staging / fp32 [2][128] pool partials.
    __shared__ unsigned short s1[2 * 9216];   // 36864 B
    __shared__ float sVec[320];
    __shared__ float sX2[2][100];
    __shared__ float sG2[2][80];
    __shared__ int sTL2[2][V], sLT2[2][V], sMaskV2[2][V];
    __shared__ float sValidF2[2];

    const int tid = threadIdx.x;
    const int lane = tid & 63, wid = tid >> 6;
    const int rsel = wid >> 1;                // which row this wave serves
    const int vw = wid & 1;                   // wave index within the row
    const int lrow = lane & 15;
    const int kq = (lane >> 4) * 8;           // k-offset within a 32-chunk
    const int rrow = (lane >> 4) * 4;         // D row base within 16-tile
    const size_t r0 = (size_t)blockIdx.x * 2;

    float* outp  = out;
    float* maskp = out + (size_t)NROWS * HDIM;
    float* posp  = maskp + NROWS;

    unsigned short* s1r = s1 + rsel * 9216;

    // zero s1 (phase B reads zero-padded K in [20,32))
    {
        uint4* p = (uint4*)s1;               // 36864 B = 2304 uint4
        uint4 z; z.x = z.y = z.z = z.w = 0u;
        for (int i = tid; i < 2304; i += 256) p[i] = z;
    }

    if (tid < 100)                     sX2[0][tid]       = x[r0 * 100 + tid];
    else if (tid >= 128 && tid < 228)  sX2[1][tid - 128] = x[(r0 + 1) * 100 + (tid - 128)];
    __syncthreads();

    {
        int rowi = -1, v = 0;
        if (tid < V)                      { rowi = 0; v = tid; }
        else if (tid >= 128 && tid < 128 + V) { rowi = 1; v = tid - 128; }
        if (rowi >= 0) {
            float x0 = sX2[rowi][v * 5 + 0], x1 = sX2[rowi][v * 5 + 1], hd = sX2[rowi][v * 5 + 2];
            float chv = cosf(hd), shv = sinf(hd);
            sG2[rowi][v * 4 + 0] = x0; sG2[rowi][v * 4 + 1] = x1;
            sG2[rowi][v * 4 + 2] = chv; sG2[rowi][v * 4 + 3] = shv;
            int nz = (x0 != 0.f) + (x1 != 0.f) + (chv != 0.f) + (shv != 0.f);
            sMaskV2[rowi][v] = (nz == 0);
            int tl = (int)sX2[rowi][v * 5 + 3]; tl = tl < 0 ? 0 : (tl > 8 ? 8 : tl);
            int lt = (int)sX2[rowi][v * 5 + 4]; lt = lt < 0 ? 0 : (lt > 19 ? 19 : lt);
            sTL2[rowi][v] = tl; sLT2[rowi][v] = lt;
        }
    }
    __syncthreads();

    if (tid < 2) {
        const int rowi = tid;
        int mp = 1;
        for (int v = 0; v < V; ++v) mp &= sMaskV2[rowi][v];
        sValidF2[rowi] = mp ? 0.f : 1.f;
        maskp[r0 + rowi] = mp ? 1.f : 0.f;
        posp[(r0 + rowi) * 5 + 0] = sX2[rowi][50];
        posp[(r0 + rowi) * 5 + 1] = sX2[rowi][51];
        posp[(r0 + rowi) * 5 + 2] = sX2[rowi][52];
        posp[(r0 + rowi) * 5 + 3] = sX2[rowi][53] * (1.f / 8.f);
        posp[(r0 + rowi) * 5 + 4] = sX2[rowi][54] * (1.f / 19.f);
    }

    // ==== Phase A: h0 = gelu(g@W1+b1); f0 = h0@chfc2 (+b+tables) -> s1r[c*72+v]
    // Wave covers 4 c-tiles: c-rows [64vw, 64vw+64) of its row region.
    {
        const float* sG = sG2[rsel];
        float g0[4], g1[4];
        const bool v1ok = (lrow < 4);
        const int v0 = lrow, v1 = 16 + lrow;
#pragma unroll
        for (int i = 0; i < 4; ++i) {
            g0[i] = sG[v0 * 4 + i];
            g1[i] = v1ok ? sG[v1 * 4 + i] : 0.f;
        }
        floatx4 acc[2][4];
#pragma unroll
        for (int mt = 0; mt < 2; ++mt)
#pragma unroll
            for (int ni = 0; ni < 4; ++ni) acc[mt][ni] = {0.f, 0.f, 0.f, 0.f};
        const unsigned short* wB = ws + WS_CHFC2;
#pragma unroll 1
        for (int kc = 0; kc < 4; ++kc) {
            union { unsigned short u[8]; bf16x8 v; } p0, p1;
            const int kb = kc * 32 + kq;
#pragma unroll
            for (int j = 0; j < 8; ++j) {
                const float w0 = ch_fc1_w[0 * C + kb + j];
                const float w1 = ch_fc1_w[1 * C + kb + j];
                const float w2 = ch_fc1_w[2 * C + kb + j];
                const float w3 = ch_fc1_w[3 * C + kb + j];
                const float bb = ch_fc1_b[kb + j];
                float h0 = fmaf(g0[0], w0, fmaf(g0[1], w1, fmaf(g0[2], w2, fmaf(g0[3], w3, bb))));
                p0.u[j] = f2bf(gelu(h0));
                if (v1ok) {
                    float h1 = fmaf(g1[0], w0, fmaf(g1[1], w1, fmaf(g1[2], w2, fmaf(g1[3], w3, bb))));
                    p1.u[j] = f2bf(gelu(h1));
                } else p1.u[j] = 0;
            }
#pragma unroll
            for (int ni = 0; ni < 4; ++ni) {
                const int n = (4 * vw + ni) * 16 + lrow;
                bf16x8 b = *(const bf16x8*)(wB + n * 128 + kc * 32 + kq);
                acc[0][ni] = mfma16(p0.v, b, acc[0][ni]);
                acc[1][ni] = mfma16(p1.v, b, acc[1][ni]);
            }
        }
#pragma unroll
        for (int ni = 0; ni < 4; ++ni) {
            const int c = (4 * vw + ni) * 16 + lrow;
            const float bb = ch_fc2_b[c];
#pragma unroll
            for (int mt = 0; mt < 2; ++mt)
#pragma unroll
                for (int rr = 0; rr < 4; ++rr) {
                    const int v = mt * 16 + rrow + rr;
                    if (v < V) {
                        float val = acc[mt][ni][rr] + bb
                                  + tl_table[sTL2[rsel][v] * C + c] + lane_table[sLT2[rsel][v] * C + c];
                        s1r[c * 72 + v] = f2bf(val);
                    }
                }
        }
    }
    // wave-local chain: phase A wrote c-rows [64vw,64vw+64); phase B reads same.

    // ==== Phase B: expand fc1 (K=32 padded), in-place gelu into s1r[c*72 + t]
    {
        bf16x8 bw[4];
        const unsigned short* wB = ws + WS_TOKFC1;
#pragma unroll
        for (int nt = 0; nt < 4; ++nt)
            bw[nt] = *(const bf16x8*)(wB + (nt * 16 + lrow) * 32 + kq);
#pragma unroll 1
        for (int mt = 0; mt < 4; ++mt) {
            const int m = 64 * vw + 16 * mt + lrow;
            bf16x8 af = *(const bf16x8*)(s1r + m * 72 + kq);
            floatx4 acc[4];
#pragma unroll
            for (int nt = 0; nt < 4; ++nt) acc[nt] = {0.f, 0.f, 0.f, 0.f};
#pragma unroll
            for (int nt = 0; nt < 4; ++nt) acc[nt] = mfma16(af, bw[nt], acc[nt]);
#pragma unroll
            for (int nt = 0; nt < 4; ++nt) {
                const int t = nt * 16 + lrow;
                const float bb = tok_fc1_b[t];
#pragma unroll
                for (int rr = 0; rr < 4; ++rr)
                    s1r[(64 * vw + 16 * mt + rrow + rr) * 72 + t] = f2bf(gelu(acc[nt][rr] + bb));
            }
        }
    }
    __syncthreads();   // phase C reads all rows of the row region

    // ==== residual in registers: R[2 m-tiles][8 n-tiles] floatx4 ====
    floatx4 R[2][8];
#pragma unroll
    for (int mt = 0; mt < 2; ++mt)
#pragma unroll
        for (int nt = 0; nt < 8; ++nt) R[mt][nt] = {0.f, 0.f, 0.f, 0.f};

    tok_fc2_R2(s1r, ws + WS_TOKFC2, tok_fc2_b, R, vw, lrow, kq, rrow);

    // ==== Mixer blocks ====
#pragma unroll 1
    for (int blk = 0; blk < DEPTH; ++blk) {
        __syncthreads();   // prior cross-wave s1 reads done before ln1 overwrites
        ln_reg2(R, bn1w + blk * C, bn1b + blk * C, s1r, vw, lrow, rrow, true);
        __syncthreads();   // ln1 all-scatter visible
        tok_fc1_g2(s1r, ws + WS_BTOK1 + blk * 4096, btok1b + blk * T, vw, lrow, kq, rrow);
        __syncthreads();   // tok_fc1 stripes visible (tok_fc2 reads all rows)
        tok_fc2_R2(s1r, ws + WS_BTOK2 + blk * 4096, btok2b + blk * T, R, vw, lrow, kq, rrow);
        __syncthreads();   // tok_fc2 cross-wave reads done before ln2 overwrites
        ln_reg2(R, bn2w + blk * C, bn2b + blk * C, s1r, vw, lrow, rrow, false);
        // ln2 writes t-rows [32vw,32vw+32) (wave-local); ch chain stays wave-local:
        ch_fc1_g2(s1r, ws + WS_BCH1 + blk * 16384, bch1b + blk * C, vw, lrow, kq, rrow);
        ch_fc2_R2(s1r, ws + WS_BCH2 + blk * 16384, bch2b + blk * C, R, vw, lrow, kq, rrow);
    }
    __syncthreads();   // all ch_fc2 reads done before s1 reuse as pool buffer

    // ==== mean over tokens (from R) + final LN + head, per row ====
    float* P = (float*)s1;   // [2 rows][2 waves][128] fp32 partials
    {
        float snt[8];
#pragma unroll
        for (int nt = 0; nt < 8; ++nt)
            snt[nt] = ((R[0][nt][0] + R[0][nt][1]) + (R[0][nt][2] + R[0][nt][3]))
                    + ((R[1][nt][0] + R[1][nt][1]) + (R[1][nt][2] + R[1][nt][3]));
#pragma unroll
        for (int nt = 0; nt < 8; ++nt) {
            snt[nt] += __shfl_xor(snt[nt], 16);
            snt[nt] += __shfl_xor(snt[nt], 32);
        }
        if (lane < 16) {
#pragma unroll
            for (int nt = 0; nt < 8; ++nt)
                P[rsel * 256 + vw * 128 + 16 * nt + lane] = snt[nt];
        }
    }
    __syncthreads();

#pragma unroll 1
    for (int rowi = 0; rowi < 2; ++rowi) {
        float fm = 0.f;
        if (tid < C) {
            fm = (P[rowi * 256 + tid] + P[rowi * 256 + 128 + tid]) * (1.f / 64.f);
            sVec[tid] = fm;
        }
        __syncthreads();
        {
            float s = 0.f, q = 0.f;
#pragma unroll
            for (int c = 0; c < C; c += 4) {
                float4 v = *(const float4*)(sVec + c);
                s += (v.x + v.y) + (v.z + v.w);
                q += v.x * v.x + v.y * v.y + v.z * v.z + v.w * v.w;
            }
            __syncthreads();
            const float m = s * (1.f / 128.f);
            const float rs = rsqrtf(q * (1.f / 128.f) - m * m + 1e-5f);
            if (tid < C) sVec[tid] = (fm - m) * rs * norm_w[tid] + norm_b[tid];
        }
        __syncthreads();

        if (tid < HDIM) {
            float a0 = 0.f, a1 = 0.f, a2 = 0.f, a3 = 0.f;
#pragma unroll 4
            for (int c = 0; c < C; c += 4) {
                float4 sv = *(const float4*)(sVec + c);
                a0 = fmaf(sv.x, emb1w[(c + 0) * HDIM + tid], a0);
                a1 = fmaf(sv.y, emb1w[(c + 1) * HDIM + tid], a1);
                a2 = fmaf(sv.z, emb1w[(c + 2) * HDIM + tid], a2);
                a3 = fmaf(sv.w, emb1w[(c + 3) * HDIM + tid], a3);
            }
            sVec[C + tid] = gelu(((a0 + a1) + (a2 + a3)) + emb1b[tid]);
        }
        __syncthreads();
        if (tid < HDIM) {
            float a0 = 0.f, a1 = 0.f, a2 = 0.f, a3 = 0.f;
#pragma unroll 4
            for (int j = 0; j < HDIM; j += 4) {
                float4 sv = *(const float4*)(sVec + C + j);
                a0 = fmaf(sv.x, emb2w[(j + 0) * HDIM + tid], a0);
                a1 = fmaf(sv.y, emb2w[(j + 1) * HDIM + tid], a1);
                a2 = fmaf(sv.z, emb2w[(j + 2) * HDIM + tid], a2);
                a3 = fmaf(sv.w, emb2w[(j + 3) * HDIM + tid], a3);
            }
            outp[(r0 + rowi) * HDIM + tid] = (((a0 + a1) + (a2 + a3)) + emb2b[tid]) * sValidF2[rowi];
        }
        __syncthreads();   // sVec reads done before next rowi overwrites
    }
}

// ================= fallback scalar kernel (R1 version) =================
template<int K, int LDA, int N>
__device__ __forceinline__ void gemm_bf(const unsigned short* __restrict__ A,
                                        const float* __restrict__ W,
                                        float acc[4][8])
{
#pragma unroll 2
    for (int k = 0; k < K; k += 4) {
        float a[4][4];
#pragma unroll
        for (int i = 0; i < 4; ++i) {
            ushort4 raw = *(const ushort4*)(A + i * LDA + k);
            a[i][0] = bf2f(raw.x); a[i][1] = bf2f(raw.y);
            a[i][2] = bf2f(raw.z); a[i][3] = bf2f(raw.w);
        }
#pragma unroll
        for (int kk = 0; kk < 4; ++kk) {
            const float* wr = W + (k + kk) * N;
            float4 w0 = *(const float4*)(wr);
            float4 w1 = *(const float4*)(wr + 4);
#pragma unroll
            for (int i = 0; i < 4; ++i) {
                acc[i][0] = fmaf(a[i][kk], w0.x, acc[i][0]);
                acc[i][1] = fmaf(a[i][kk], w0.y, acc[i][1]);
                acc[i][2] = fmaf(a[i][kk], w0.z, acc[i][2]);
                acc[i][3] = fmaf(a[i][kk], w0.w, acc[i][3]);
                acc[i][4] = fmaf(a[i][kk], w1.x, acc[i][4]);
                acc[i][5] = fmaf(a[i][kk], w1.y, acc[i][5]);
                acc[i][6] = fmaf(a[i][kk], w1.z, acc[i][6]);
                acc[i][7] = fmaf(a[i][kk], w1.w, acc[i][7]);
            }
        }
    }
}

template<int K, int LDA, int N>
__device__ __forceinline__ void gemm_f32(const float* __restrict__ A,
                                         const float* __restrict__ W,
                                         float acc[4][8])
{
#pragma unroll
    for (int k = 0; k < K; k += 4) {
        float a[4][4];
#pragma unroll
        for (int i = 0; i < 4; ++i) {
            float4 v = *(const float4*)(A + i * LDA + k);
            a[i][0] = v.x; a[i][1] = v.y; a[i][2] = v.z; a[i][3] = v.w;
        }
#pragma unroll
        for (int kk = 0; kk < 4; ++kk) {
            const float* wr = W + (k + kk) * N;
            float4 w0 = *(const float4*)(wr);
            float4 w1 = *(const float4*)(wr + 4);
#pragma unroll
            for (int i = 0; i < 4; ++i) {
                acc[i][0] = fmaf(a[i][kk], w0.x, acc[i][0]);
                acc[i][1] = fmaf(a[i][kk], w0.y, acc[i][1]);
                acc[i][2] = fmaf(a[i][kk], w0.z, acc[i][2]);
                acc[i][3] = fmaf(a[i][kk], w0.w, acc[i][3]);
                acc[i][4] = fmaf(a[i][kk], w1.x, acc[i][4]);
                acc[i][5] = fmaf(a[i][kk], w1.y, acc[i][5]);
                acc[i][6] = fmaf(a[i][kk], w1.z, acc[i][6]);
                acc[i][7] = fmaf(a[i][kk], w1.w, acc[i][7]);
            }
        }
    }
}

__global__ __launch_bounds__(256, 3)
void lanefusion_scalar(
    const float* __restrict__ x,
    const float* __restrict__ tl_table, const float* __restrict__ lane_table,
    const float* __restrict__ ch_fc1_w, const float* __restrict__ ch_fc1_b,
    const float* __restrict__ ch_fc2_w, const float* __restrict__ ch_fc2_b,
    const float* __restrict__ tok_fc1_w, const float* __restrict__ tok_fc1_b,
    const float* __restrict__ tok_fc2_w, const float* __restrict__ tok_fc2_b,
    const float* __restrict__ bn1w, const float* __restrict__ bn1b,
    const float* __restrict__ btok1w, const float* __restrict__ btok1b,
    const float* __restrict__ btok2w, const float* __restrict__ btok2b,
    const float* __restrict__ bn2w, const float* __restrict__ bn2b,
    const float* __restrict__ bch1w, const float* __restrict__ bch1b,
    const float* __restrict__ bch2w, const float* __restrict__ bch2b,
    const float* __restrict__ norm_w, const float* __restrict__ norm_b,
    const float* __restrict__ emb1w, const float* __restrict__ emb1b,
    const float* __restrict__ emb2w, const float* __restrict__ emb2b,
    float* __restrict__ out)
{
    __shared__ float sF[T * 132];
    __shared__ unsigned short sA[8704];
    __shared__ float sVec[320];
    __shared__ int sTL[V], sLT[V], sMaskV[V];
    __shared__ float sValidF;

    const int tid = threadIdx.x;
    const int r = blockIdx.x;

    float* outp  = out;
    float* maskp = out + (size_t)NROWS * HDIM;
    float* posp  = maskp + NROWS;

    float* sX = sVec;
    float* sG = sVec + 128;

    const float* xr = x + (size_t)r * (V * 5);
    if (tid < V * 5) sX[tid] = xr[tid];
    __syncthreads();

    if (tid < V) {
        float x0 = sX[tid * 5 + 0], x1 = sX[tid * 5 + 1], hd = sX[tid * 5 + 2];
        float chv = cosf(hd), shv = sinf(hd);
        sG[tid * 4 + 0] = x0; sG[tid * 4 + 1] = x1;
        sG[tid * 4 + 2] = chv; sG[tid * 4 + 3] = shv;
        int nz = (x0 != 0.f) + (x1 != 0.f) + (chv != 0.f) + (shv != 0.f);
        sMaskV[tid] = (nz == 0);
        int tl = (int)sX[tid * 5 + 3]; tl = tl < 0 ? 0 : (tl > 8 ? 8 : tl);
        int lt = (int)sX[tid * 5 + 4]; lt = lt < 0 ? 0 : (lt > 19 ? 19 : lt);
        sTL[tid] = tl; sLT[tid] = lt;
    }
    __syncthreads();

    if (tid == 0) {
        int mp = 1;
        for (int v = 0; v < V; ++v) mp &= sMaskV[v];
        sValidF = mp ? 0.f : 1.f;
        maskp[r] = mp ? 1.f : 0.f;
        posp[(size_t)r * 5 + 0] = sX[50];
        posp[(size_t)r * 5 + 1] = sX[51];
        posp[(size_t)r * 5 + 2] = sX[52];
        posp[(size_t)r * 5 + 3] = sX[53] * (1.f / 8.f);
        posp[(size_t)r * 5 + 4] = sX[54] * (1.f / 19.f);
    }

    if (tid < 160) {
        const int v = tid >> 3, c0 = (tid & 7) * 16;
        const float g0 = sG[v * 4 + 0], g1 = sG[v * 4 + 1],
                    g2 = sG[v * 4 + 2], g3 = sG[v * 4 + 3];
#pragma unroll
        for (int j = 0; j < 16; ++j) {
            const int c = c0 + j;
            float s = ch_fc1_b[c];
            s = fmaf(g0, ch_fc1_w[0 * C + c], s);
            s = fmaf(g1, ch_fc1_w[1 * C + c], s);
            s = fmaf(g2, ch_fc1_w[2 * C + c], s);
            s = fmaf(g3, ch_fc1_w[3 * C + c], s);
            sA[v * 132 + c] = f2bf(gelu(s));
        }
    }
    __syncthreads();

    if (tid < 160) {
        const int v = tid >> 3, c0 = (tid & 7) * 16;
        float acc[16];
#pragma unroll
        for (int j = 0; j < 16; ++j) acc[j] = 0.f;
        const unsigned short* Arow = sA + v * 132;
        for (int k = 0; k < C; k += 4) {
            ushort4 raw = *(const ushort4*)(Arow + k);
            float a4[4] = { bf2f(raw.x), bf2f(raw.y), bf2f(raw.z), bf2f(raw.w) };
#pragma unroll
            for (int kk = 0; kk < 4; ++kk) {
                const float* wr = ch_fc2_w + (k + kk) * C + c0;
                float4 w0 = *(const float4*)(wr);
                float4 w1 = *(const float4*)(wr + 4);
                float4 w2 = *(const float4*)(wr + 8);
                float4 w3 = *(const float4*)(wr + 12);
                acc[0]  = fmaf(a4[kk], w0.x, acc[0]);  acc[1]  = fmaf(a4[kk], w0.y, acc[1]);
                acc[2]  = fmaf(a4[kk], w0.z, acc[2]);  acc[3]  = fmaf(a4[kk], w0.w, acc[3]);
                acc[4]  = fmaf(a4[kk], w1.x, acc[4]);  acc[5]  = fmaf(a4[kk], w1.y, acc[5]);
                acc[6]  = fmaf(a4[kk], w1.z, acc[6]);  acc[7]  = fmaf(a4[kk], w1.w, acc[7]);
                acc[8]  = fmaf(a4[kk], w2.x, acc[8]);  acc[9]  = fmaf(a4[kk], w2.y, acc[9]);
                acc[10] = fmaf(a4[kk], w2.z, acc[10]); acc[11] = fmaf(a4[kk], w2.w, acc[11]);
                acc[12] = fmaf(a4[kk], w3.x, acc[12]); acc[13] = fmaf(a4[kk], w3.y, acc[13]);
                acc[14] = fmaf(a4[kk], w3.z, acc[14]); acc[15] = fmaf(a4[kk], w3.w, acc[15]);
            }
        }
        const int tl = sTL[v], lt = sLT[v];
#pragma unroll
        for (int j = 0; j < 16; ++j) {
            const int c = c0 + j;
            sF[c * 20 + v] = acc[j] + ch_fc2_b[c] + tl_table[tl * C + c] + lane_table[lt * C + c];
        }
    }
    __syncthreads();

    {
        const int r0 = (tid >> 3) * 4, c0 = (tid & 7) * 8;
        float acc[4][8] = {};
        gemm_f32<20, 20, 64>(sF + r0 * 20, tok_fc1_w + c0, acc);
#pragma unroll
        for (int i = 0; i < 4; ++i)
#pragma unroll
            for (int j = 0; j < 8; ++j)
                sA[(r0 + i) * 68 + c0 + j] = f2bf(gelu(acc[i][j] + tok_fc1_b[c0 + j]));
    }
    __syncthreads();

    {
        const int r0 = (tid >> 3) * 4, c0 = (tid & 7) * 8;
        float acc[4][8] = {};
        gemm_bf<64, 68, 64>(sA + r0 * 68, tok_fc2_w + c0, acc);
#pragma unroll
        for (int i = 0; i < 4; ++i)
#pragma unroll
            for (int j = 0; j < 8; ++j)
                sF[(c0 + j) * 132 + (r0 + i)] = acc[i][j] + tok_fc2_b[c0 + j];
    }
    __syncthreads();

    for (int blk = 0; blk < DEPTH; ++blk) {
        layer_norm_to(sF, sA, bn1w + blk * C, bn1b + blk * C, tid, true, 68);
        __syncthreads();
        {
            const int r0 = (tid >> 3) * 4, c0 = (tid & 7) * 8;
            float acc[4][8] = {};
            gemm_bf<64, 68, 64>(sA + r0 * 68, btok1w + blk * T * T + c0, acc);
#pragma unroll
            for (int i = 0; i < 4; ++i)
#pragma unroll
                for (int j = 0; j < 8; ++j)
                    acc[i][j] = gelu(acc[i][j] + btok1b[blk * T + c0 + j]);
            __syncthreads();
#pragma unroll
            for (int i = 0; i < 4; ++i)
#pragma unroll
                for (int j = 0; j < 8; ++j)
                    sA[(r0 + i) * 68 + c0 + j] = f2bf(acc[i][j]);
        }
        __syncthreads();
        {
            const int r0 = (tid >> 3) * 4, c0 = (tid & 7) * 8;
            float acc[4][8] = {};
            gemm_bf<64, 68, 64>(sA + r0 * 68, btok2w + blk * T * T + c0, acc);
#pragma unroll
            for (int i = 0; i < 4; ++i)
#pragma unroll
                for (int j = 0; j < 8; ++j)
                    sF[(c0 + j) * 132 + (r0 + i)] += acc[i][j] + btok2b[blk * T + c0 + j];
        }
        __syncthreads();

        layer_norm_to(sF, sA, bn2w + blk * C, bn2b + blk * C, tid, false, 132);
        __syncthreads();
        {
            const int r0 = (tid >> 4) * 4, c0 = (tid & 15) * 8;
            float acc[4][8] = {};
            gemm_bf<128, 132, 128>(sA + r0 * 132, bch1w + blk * C * C + c0, acc);
#pragma unroll
            for (int i = 0; i < 4; ++i)
#pragma unroll
                for (int j = 0; j < 8; ++j)
                    acc[i][j] = gelu(acc[i][j] + bch1b[blk * C + c0 + j]);
            __syncthreads();
#pragma unroll
            for (int i = 0; i < 4; ++i)
#pragma unroll
                for (int j = 0; j < 8; ++j)
                    sA[(r0 + i) * 132 + c0 + j] = f2bf(acc[i][j]);
        }
        __syncthreads();
        {
            const int r0 = (tid >> 4) * 4, c0 = (tid & 15) * 8;
            float acc[4][8] = {};
            gemm_bf<128, 132, 128>(sA + r0 * 132, bch2w + blk * C * C + c0, acc);
#pragma unroll
            for (int i = 0; i < 4; ++i)
#pragma unroll
                for (int j = 0; j < 8; ++j)
                    sF[(r0 + i) * 132 + c0 + j] += acc[i][j] + bch2b[blk * C + c0 + j];
        }
        __syncthreads();
    }

    float fm = 0.f;
    if (tid < C) {
#pragma unroll 8
        for (int t = 0; t < T; ++t) fm += sF[t * 132 + tid];
        fm *= (1.f / 64.f);
        sVec[tid] = fm;
    }
    __syncthreads();
    {
        float s = 0.f, q = 0.f;
        for (int c = 0; c < C; ++c) { float v = sVec[c]; s += v; q += v * v; }
        __syncthreads();
        const float m = s * (1.f / 128.f);
        const float rs = rsqrtf(q * (1.f / 128.f) - m * m + 1e-5f);
        if (tid < C) sVec[tid] = (fm - m) * rs * norm_w[tid] + norm_b[tid];
    }
    __syncthreads();

    if (tid < HDIM) {
        float v1 = emb1b[tid];
        for (int c = 0; c < C; ++c) v1 = fmaf(sVec[c], emb1w[c * HDIM + tid], v1);
        sVec[C + tid] = gelu(v1);
    }
    __syncthreads();
    if (tid < HDIM) {
        float v2 = emb2b[tid];
        for (int j = 0; j < HDIM; ++j) v2 = fmaf(sVec[C + j], emb2w[j * HDIM + tid], v2);
        outp[(size_t)r * HDIM + tid] = v2 * sValidF;
    }
}

extern "C" void kernel_launch(void* const* d_in, const int* in_sizes, int n_in,
                              void* d_out, int out_size, void* d_ws, size_t ws_size,
                              hipStream_t stream) {
    (void)in_sizes; (void)n_in; (void)out_size;
    if (ws_size >= (size_t)WS_TOTAL * 2) {
        prep_weights<<<dim3((WS_TOTAL + 255) / 256), dim3(256), 0, stream>>>(
            (const float*)d_in[7],  // tok_fc1_w
            (const float*)d_in[9],  // tok_fc2_w
            (const float*)d_in[13], // blk_tok_fc1_w
            (const float*)d_in[15], // blk_tok_fc2_w
            (const float*)d_in[5],  // ch_fc2_w
            (const float*)d_in[19], // blk_ch_fc1_w
            (const float*)d_in[21], // blk_ch_fc2_w
            (unsigned short*)d_ws);
        lanefusion_mfma<<<dim3(NROWS / 2), dim3(256), 0, stream>>>(
            (const float*)d_in[0],  (const float*)d_in[1],  (const float*)d_in[2],
            (const float*)d_in[3],  (const float*)d_in[4],
            (const float*)d_in[6],
            (const float*)d_in[8],  (const float*)d_in[10],
            (const float*)d_in[11], (const float*)d_in[12],
            (const float*)d_in[14], (const float*)d_in[16],
            (const float*)d_in[17], (const float*)d_in[18],
            (const float*)d_in[20], (const float*)d_in[22],
            (const float*)d_in[23], (const float*)d_in[24],
            (const float*)d_in[25], (const float*)d_in[26],
            (const float*)d_in[27], (const float*)d_in[28],
            (const unsigned short*)d_ws,
            (float*)d_out);
    } else {
        lanefusion_scalar<<<dim3(NROWS), dim3(256), 0, stream>>>(
            (const float*)d_in[0],  (const float*)d_in[1],  (const float*)d_in[2],
            (const float*)d_in[3],  (const float*)d_in[4],  (const float*)d_in[5],
            (const float*)d_in[6],  (const float*)d_in[7],  (const float*)d_in[8],
            (const float*)d_in[9],  (const float*)d_in[10], (const float*)d_in[11],
            (const float*)d_in[12], (const float*)d_in[13], (const float*)d_in[14],
            (const float*)d_in[15], (const float*)d_in[16], (const float*)d_in[17],
            (const float*)d_in[18], (const float*)d_in[19], (const float*)d_in[20],
            (const float*)d_in[21], (const float*)d_in[22], (const float*)d_in[23],
            (const float*)d_in[24], (const float*)d_in[25], (const float*)d_in[26],
            (const float*)d_in[27], (const float*)d_in[28],
            (float*)d_out);
    }
}

// Round 10
// 1120.762 us; speedup vs baseline: 1.1127x; 1.1127x over previous
//
#include <hip/hip_runtime.h>

#define NROWS 8192
#define V 20
#define C 128
#define T 64
#define HDIM 192
#define DEPTH 3

typedef __attribute__((ext_vector_type(8))) short bf16x8;
typedef __attribute__((ext_vector_type(4))) float floatx4;

// ---- ws segment offsets (bf16 elements), all W^T [N][K] ----
#define WS_TOKFC1 0        // [64][32]  (k>=20 zero-padded)
#define WS_TOKFC2 2048     // [64][64]
#define WS_BTOK1  6144     // [3][64][64]
#define WS_BTOK2  18432    // [3][64][64]
#define WS_CHFC2  30720    // [128][128]
#define WS_BCH1   47104    // [3][128][128]
#define WS_BCH2   96256    // [3][128][128]
#define WS_TOTAL  145408   // elements -> 290816 bytes

// ---------- helpers ----------
__device__ __forceinline__ float bf2f(unsigned short u) {
    union { unsigned int i; float f; } c; c.i = ((unsigned int)u) << 16; return c.f;
}
__device__ __forceinline__ unsigned short f2bf(float f) {
    union { float f; unsigned int i; } c; c.f = f;
    unsigned int r = c.i + 0x7fffu + ((c.i >> 16) & 1u);  // RNE
    return (unsigned short)(r >> 16);
}
// Fast GELU (tanh form): x * sigmoid(1.59576912*(x + 0.044715 x^3)).
__device__ __forceinline__ float gelu(float x) {
    float u = x * x;
    float p = fmaf(u, 0.044715f, 1.0f);
    float arg = x * p * -2.3022042f;   // -1.59576912 * log2(e)
    float e = __builtin_amdgcn_exp2f(arg);
    return x * __builtin_amdgcn_rcpf(1.0f + e);
}
__device__ __forceinline__ floatx4 mfma16(bf16x8 a, bf16x8 b, floatx4 c) {
    return __builtin_amdgcn_mfma_f32_16x16x32_bf16(a, b, c, 0, 0, 0);
}

// ================== register-residual building blocks (lean-liveness) ======
// Residual ownership: thread (wid, lane) owns token t = 16*wid + rrow + rr,
// channel c = 16*nt + lrow  ->  R[nt][rr], 8 floatx4 = 32 fp32 per thread.
// BOTH fc2 GEMMs are oriented so their MFMA C/D layout == R's layout, so R
// itself is the MFMA accumulator (no separate acc, no LDS redistribution).

// LayerNorm from registers; writes normalized bf16 to s1.
// transposed=true  -> s1[c*72 + t]   (token-GEMM staging)
// transposed=false -> s1[t*136 + c]  (channel-GEMM staging)
__device__ __forceinline__ void ln_reg(const floatx4 (&R)[8],
                                       const float* __restrict__ w,
                                       const float* __restrict__ b,
                                       unsigned short* __restrict__ s1,
                                       int wid, int lrow, int rrow, bool transposed)
{
    float s[4], q[4];
#pragma unroll
    for (int rr = 0; rr < 4; ++rr) {
        float ss = 0.f, qq = 0.f;
#pragma unroll
        for (int nt = 0; nt < 8; ++nt) { float v = R[nt][rr]; ss += v; qq += v * v; }
        s[rr] = ss; q[rr] = qq;
    }
    // per-token reduce across the 16 lanes sharing a token (lanes differ in lrow)
#pragma unroll
    for (int rr = 0; rr < 4; ++rr) {
        s[rr] += __shfl_xor(s[rr], 1);  q[rr] += __shfl_xor(q[rr], 1);
        s[rr] += __shfl_xor(s[rr], 2);  q[rr] += __shfl_xor(q[rr], 2);
        s[rr] += __shfl_xor(s[rr], 4);  q[rr] += __shfl_xor(q[rr], 4);
        s[rr] += __shfl_xor(s[rr], 8);  q[rr] += __shfl_xor(q[rr], 8);
    }
    float m[4], rs[4];
#pragma unroll
    for (int rr = 0; rr < 4; ++rr) {
        m[rr] = s[rr] * (1.f / 128.f);
        rs[rr] = rsqrtf(q[rr] * (1.f / 128.f) - m[rr] * m[rr] + 1e-5f);
    }
#pragma unroll
    for (int nt = 0; nt < 8; ++nt) {
        const int c = 16 * nt + lrow;
        const float wv = w[c], bv = b[c];
#pragma unroll
        for (int rr = 0; rr < 4; ++rr) {
            const int t = 16 * wid + rrow + rr;
            unsigned short o = f2bf((R[nt][rr] - m[rr]) * rs[rr] * wv + bv);
            if (transposed) s1[c * 72 + t] = o;
            else            s1[t * 136 + c] = o;
        }
    }
}

// token fc1 (K=64): A = s1 [c][t] wave stripe, gelu, in-place write.
// Split by mt so transient acc is only 4 floatx4 (16 regs) while R idles.
// In-place safe: mt=0 writes rows [32w,32w+16) before mt=1 reads [32w+16,32w+32).
__device__ __forceinline__ void tok_fc1_gelu(unsigned short* __restrict__ s1,
                                             const unsigned short* __restrict__ wB,
                                             const float* __restrict__ bias,
                                             int wid, int lrow, int kq, int rrow)
{
#pragma unroll
    for (int mt = 0; mt < 2; ++mt) {
        bf16x8 at[2];
#pragma unroll
        for (int kc = 0; kc < 2; ++kc)
            at[kc] = *(const bf16x8*)(s1 + (32 * wid + mt * 16 + lrow) * 72 + kc * 32 + kq);
        floatx4 acc[4];
#pragma unroll
        for (int nt = 0; nt < 4; ++nt) acc[nt] = {0.f, 0.f, 0.f, 0.f};
#pragma unroll
        for (int nt = 0; nt < 4; ++nt)
#pragma unroll
            for (int kc = 0; kc < 2; ++kc) {
                bf16x8 b = *(const bf16x8*)(wB + (nt * 16 + lrow) * 64 + kc * 32 + kq);
                acc[nt] = mfma16(at[kc], b, acc[nt]);
            }
#pragma unroll
        for (int nt = 0; nt < 4; ++nt) {
            const int t = nt * 16 + lrow;
            const float bb = bias[t];
#pragma unroll
            for (int rr = 0; rr < 4; ++rr)
                s1[(32 * wid + mt * 16 + rrow + rr) * 72 + t] = f2bf(gelu(acc[nt][rr] + bb));
        }
    }
}

// token fc2 (K=64), OPERAND-SWAPPED: D[m=t'][n=c] = W[t'][t] * X^T[c][t].
// Wave wid owns m-tile t' in [16w,16w+16); n spans all 8 c-tiles.
// D layout == R layout exactly -> R is the MFMA accumulator (seeded C-in).
// Reads s1 rows across ALL waves: caller must barrier before AND after.
__device__ __forceinline__ void tok_fc2_to_R(const unsigned short* __restrict__ s1,
                                             const unsigned short* __restrict__ wB,
                                             const float* __restrict__ bias,
                                             floatx4 (&R)[8],
                                             int wid, int lrow, int kq, int rrow)
{
    bf16x8 aw[2];
#pragma unroll
    for (int kc = 0; kc < 2; ++kc)
        aw[kc] = *(const bf16x8*)(wB + (16 * wid + lrow) * 64 + kc * 32 + kq);
    float bb[4];
#pragma unroll
    for (int rr = 0; rr < 4; ++rr) bb[rr] = bias[16 * wid + rrow + rr];
#pragma unroll
    for (int nt = 0; nt < 8; ++nt) {
        floatx4 acc = R[nt];
#pragma unroll
        for (int kc = 0; kc < 2; ++kc) {
            bf16x8 b = *(const bf16x8*)(s1 + (16 * nt + lrow) * 72 + kc * 32 + kq);
            acc = mfma16(aw[kc], b, acc);
        }
#pragma unroll
        for (int rr = 0; rr < 4; ++rr) acc[rr] += bb[rr];
        R[nt] = acc;
    }
}

// channel fc1 (K=128): A = s1 [t][c] wave rows, gelu, in-place.
// Split into 4 groups of 2 n-tiles: transient acc = 2 floatx4 (8 regs).
__device__ __forceinline__ void ch_fc1_gelu(unsigned short* __restrict__ s1,
                                            const unsigned short* __restrict__ wB,
                                            const float* __restrict__ bias,
                                            int wid, int lrow, int kq, int rrow)
{
    bf16x8 a2[4];
    const int m = 16 * wid + lrow;
#pragma unroll
    for (int kc = 0; kc < 4; ++kc)
        a2[kc] = *(const bf16x8*)(s1 + m * 136 + kc * 32 + kq);
#pragma unroll
    for (int g = 0; g < 4; ++g) {
        floatx4 acc[2];
#pragma unroll
        for (int i = 0; i < 2; ++i) acc[i] = {0.f, 0.f, 0.f, 0.f};
#pragma unroll
        for (int i = 0; i < 2; ++i) {
            const int n = (2 * g + i) * 16 + lrow;
#pragma unroll
            for (int kc = 0; kc < 4; ++kc) {
                bf16x8 b = *(const bf16x8*)(wB + n * 128 + kc * 32 + kq);
                acc[i] = mfma16(a2[kc], b, acc[i]);
            }
        }
#pragma unroll
        for (int i = 0; i < 2; ++i) {
            const int c = (2 * g + i) * 16 + lrow;
            const float bb = bias[c];
#pragma unroll
            for (int rr = 0; rr < 4; ++rr)
                s1[(16 * wid + rrow + rr) * 136 + c] = f2bf(gelu(acc[i][rr] + bb));
        }
    }
}

// channel fc2 (K=128): D[m=t][n=c] with R as seeded accumulator. Wave-local reads.
__device__ __forceinline__ void ch_fc2_to_R(const unsigned short* __restrict__ s1,
                                            const unsigned short* __restrict__ wB,
                                            const float* __restrict__ bias,
                                            floatx4 (&R)[8],
                                            int wid, int lrow, int kq, int rrow)
{
    bf16x8 a2[4];
    const int m = 16 * wid + lrow;
#pragma unroll
    for (int kc = 0; kc < 4; ++kc)
        a2[kc] = *(const bf16x8*)(s1 + m * 136 + kc * 32 + kq);
#pragma unroll
    for (int nt = 0; nt < 8; ++nt) {
        floatx4 acc = R[nt];
        const float bb = bias[16 * nt + lrow];
#pragma unroll
        for (int kc = 0; kc < 4; ++kc) {
            bf16x8 b = *(const bf16x8*)(wB + (16 * nt + lrow) * 128 + kc * 32 + kq);
            acc = mfma16(a2[kc], b, acc);
        }
#pragma unroll
        for (int rr = 0; rr < 4; ++rr) acc[rr] += bb;
        R[nt] = acc;
    }
}

// LN over C=128 per token; 4 threads/token (scalar-fallback kernel only).
__device__ __forceinline__ void layer_norm_to(const float* __restrict__ sF,
                                              unsigned short* __restrict__ sA,
                                              const float* __restrict__ w,
                                              const float* __restrict__ b,
                                              int tid, bool transposed, int strideOut)
{
    const int t = tid >> 2, part = tid & 3;
    const float* row = sF + t * 132 + part * 32;
    float s = 0.f, q = 0.f;
#pragma unroll
    for (int j = 0; j < 8; ++j) {
        float4 v = *(const float4*)(row + j * 4);
        s += (v.x + v.y) + (v.z + v.w);
        q += v.x * v.x + v.y * v.y + v.z * v.z + v.w * v.w;
    }
    s += __shfl_xor(s, 1); q += __shfl_xor(q, 1);
    s += __shfl_xor(s, 2); q += __shfl_xor(q, 2);
    const float m = s * (1.f / 128.f);
    const float rs = rsqrtf(q * (1.f / 128.f) - m * m + 1e-5f);
#pragma unroll
    for (int j = 0; j < 8; ++j) {
        float4 v = *(const float4*)(row + j * 4);
        const int c = part * 32 + j * 4;
        float4 wv = *(const float4*)(w + c);
        float4 bv = *(const float4*)(b + c);
        unsigned short o0 = f2bf((v.x - m) * rs * wv.x + bv.x);
        unsigned short o1 = f2bf((v.y - m) * rs * wv.y + bv.y);
        unsigned short o2 = f2bf((v.z - m) * rs * wv.z + bv.z);
        unsigned short o3 = f2bf((v.w - m) * rs * wv.w + bv.w);
        if (transposed) {
            sA[(c + 0) * strideOut + t] = o0;
            sA[(c + 1) * strideOut + t] = o1;
            sA[(c + 2) * strideOut + t] = o2;
            sA[(c + 3) * strideOut + t] = o3;
        } else {
            ushort4 pk; pk.x = o0; pk.y = o1; pk.z = o2; pk.w = o3;
            *(ushort4*)(sA + t * strideOut + c) = pk;
        }
    }
}

// ---------- prep: fp32 [K][N] -> bf16 W^T [N][K] in ws ----------
__global__ void prep_weights(const float* __restrict__ tokfc1,
                             const float* __restrict__ tokfc2,
                             const float* __restrict__ btok1,
                             const float* __restrict__ btok2,
                             const float* __restrict__ chfc2,
                             const float* __restrict__ bch1,
                             const float* __restrict__ bch2,
                             unsigned short* __restrict__ ws)
{
    int idx = blockIdx.x * 256 + threadIdx.x;
    if (idx >= WS_TOTAL) return;
    if (idx < 2048) {                                   // tokfc1T [64][32]
        int n = idx >> 5, k = idx & 31;
        ws[WS_TOKFC1 + idx] = (k < V) ? f2bf(tokfc1[k * 64 + n]) : 0;
        return;
    }
    idx -= 2048;
    if (idx < 4096) {                                   // tokfc2T [64][64]
        int n = idx >> 6, k = idx & 63;
        ws[WS_TOKFC2 + idx] = f2bf(tokfc2[k * 64 + n]);
        return;
    }
    idx -= 4096;
    if (idx < 12288) {                                  // btok1T [3][64][64]
        int d = idx >> 12, rem = idx & 4095, n = rem >> 6, k = rem & 63;
        ws[WS_BTOK1 + idx] = f2bf(btok1[d * 4096 + k * 64 + n]);
        return;
    }
    idx -= 12288;
    if (idx < 12288) {                                  // btok2T [3][64][64]
        int d = idx >> 12, rem = idx & 4095, n = rem >> 6, k = rem & 63;
        ws[WS_BTOK2 + idx] = f2bf(btok2[d * 4096 + k * 64 + n]);
        return;
    }
    idx -= 12288;
    if (idx < 16384) {                                  // chfc2T [128][128]
        int n = idx >> 7, k = idx & 127;
        ws[WS_CHFC2 + idx] = f2bf(chfc2[k * 128 + n]);
        return;
    }
    idx -= 16384;
    if (idx < 49152) {                                  // bch1T [3][128][128]
        int d = idx >> 14, rem = idx & 16383, n = rem >> 7, k = rem & 127;
        ws[WS_BCH1 + idx] = f2bf(bch1[d * 16384 + k * 128 + n]);
        return;
    }
    idx -= 49152;
    {                                                   // bch2T [3][128][128]
        int d = idx >> 14, rem = idx & 16383, n = rem >> 7, k = rem & 127;
        ws[WS_BCH2 + idx] = f2bf(bch2[d * 16384 + k * 128 + n]);
    }
}

// ---------- MFMA main kernel ----------
// waves_per_eu(4): min 4 waves/EU -> unified (VGPR+AGPR) budget 128/thread.
// R8 at waves_per_eu(3) measured arch=80 + AGPR~64 = ~144 unified (3 blocks/CU,
// occ 34%). The lean structure is ~16 regs from fitting 128 -> 4 blocks/CU
// (occ ~45%). Tripwire: WRITE_SIZE (R8 baseline ~7 MB; spill shows as >100 MB).
__global__ __launch_bounds__(256) __attribute__((amdgpu_waves_per_eu(4)))
void lanefusion_mfma(
    const float* __restrict__ x,
    const float* __restrict__ tl_table, const float* __restrict__ lane_table,
    const float* __restrict__ ch_fc1_w, const float* __restrict__ ch_fc1_b,
    const float* __restrict__ ch_fc2_b,
    const float* __restrict__ tok_fc1_b, const float* __restrict__ tok_fc2_b,
    const float* __restrict__ bn1w, const float* __restrict__ bn1b,
    const float* __restrict__ btok1b, const float* __restrict__ btok2b,
    const float* __restrict__ bn2w, const float* __restrict__ bn2b,
    const float* __restrict__ bch1b, const float* __restrict__ bch2b,
    const float* __restrict__ norm_w, const float* __restrict__ norm_b,
    const float* __restrict__ emb1w, const float* __restrict__ emb1b,
    const float* __restrict__ emb2w, const float* __restrict__ emb2b,
    const unsigned short* __restrict__ ws,
    float* __restrict__ out)
{
    // s1 views: bf16 [128][72] (token staging) / bf16 [64][136] (channel staging)
    //         / fp32 [4][128] (pool partials)
    __shared__ unsigned short s1[128 * 72];  // 18432 B
    __shared__ float sVec[320];
    __shared__ int sTL[V], sLT[V], sMaskV[V];
    __shared__ float sValidF;

    const int tid = threadIdx.x;
    const int r = blockIdx.x;
    const int lane = tid & 63, wid = tid >> 6;
    const int lrow = lane & 15;
    const int kq = (lane >> 4) * 8;           // k-offset within a 32-chunk
    const int rrow = (lane >> 4) * 4;         // D row base within 16-tile

    float* outp  = out;
    float* maskp = out + (size_t)NROWS * HDIM;
    float* posp  = maskp + NROWS;

    float* sX = sVec;        // [100]
    float* sG = sVec + 128;  // [80]

    // zero s1 entirely: phase B reads k in [20,32) which is never written
    // (zero-padded K); uninitialized LDS there can be NaN-patterned -> NaN*0=NaN.
    {
        uint4* p = (uint4*)s1;               // 18432 B = 1152 uint4
        uint4 z; z.x = z.y = z.z = z.w = 0u;
        for (int i = tid; i < 1152; i += 256) p[i] = z;
    }

    const float* xr = x + (size_t)r * (V * 5);
    if (tid < V * 5) sX[tid] = xr[tid];
    __syncthreads();

    if (tid < V) {
        float x0 = sX[tid * 5 + 0], x1 = sX[tid * 5 + 1], hd = sX[tid * 5 + 2];
        float chv = cosf(hd), shv = sinf(hd);
        sG[tid * 4 + 0] = x0; sG[tid * 4 + 1] = x1;
        sG[tid * 4 + 2] = chv; sG[tid * 4 + 3] = shv;
        int nz = (x0 != 0.f) + (x1 != 0.f) + (chv != 0.f) + (shv != 0.f);
        sMaskV[tid] = (nz == 0);
        int tl = (int)sX[tid * 5 + 3]; tl = tl < 0 ? 0 : (tl > 8 ? 8 : tl);
        int lt = (int)sX[tid * 5 + 4]; lt = lt < 0 ? 0 : (lt > 19 ? 19 : lt);
        sTL[tid] = tl; sLT[tid] = lt;
    }
    __syncthreads();

    if (tid == 0) {
        int mp = 1;
        for (int v = 0; v < V; ++v) mp &= sMaskV[v];
        sValidF = mp ? 0.f : 1.f;
        maskp[r] = mp ? 1.f : 0.f;
        posp[(size_t)r * 5 + 0] = sX[50];
        posp[(size_t)r * 5 + 1] = sX[51];
        posp[(size_t)r * 5 + 2] = sX[52];
        posp[(size_t)r * 5 + 3] = sX[53] * (1.f / 8.f);
        posp[(size_t)r * 5 + 4] = sX[54] * (1.f / 19.f);
    }

    // ==== Phase A: h0 = gelu(g@W1+b1) in regs; f0 = h0@chfc2 (+b+tables) -> s1[c*72+v]
    // Per-kc chunks (unroll 1) to bound liveness: pack 1 frag-pair, 2 B-loads,
    // 4 MFMA, release. Accumulation order per acc unchanged (kc ascending).
    {
        float g0[4], g1[4];
        const bool v1ok = (lrow < 4);
        const int v0 = lrow, v1 = 16 + lrow;
#pragma unroll
        for (int i = 0; i < 4; ++i) {
            g0[i] = sG[v0 * 4 + i];
            g1[i] = v1ok ? sG[v1 * 4 + i] : 0.f;
        }
        floatx4 acc[2][2];
#pragma unroll
        for (int mt = 0; mt < 2; ++mt)
#pragma unroll
            for (int ni = 0; ni < 2; ++ni) acc[mt][ni] = {0.f, 0.f, 0.f, 0.f};
        const unsigned short* wB = ws + WS_CHFC2;
#pragma unroll 1
        for (int kc = 0; kc < 4; ++kc) {
            union { unsigned short u[8]; bf16x8 v; } p0, p1;
            const int kb = kc * 32 + kq;
#pragma unroll
            for (int j = 0; j < 8; ++j) {
                const float w0 = ch_fc1_w[0 * C + kb + j];
                const float w1 = ch_fc1_w[1 * C + kb + j];
                const float w2 = ch_fc1_w[2 * C + kb + j];
                const float w3 = ch_fc1_w[3 * C + kb + j];
                const float bb = ch_fc1_b[kb + j];
                float h0 = fmaf(g0[0], w0, fmaf(g0[1], w1, fmaf(g0[2], w2, fmaf(g0[3], w3, bb))));
                p0.u[j] = f2bf(gelu(h0));
                if (v1ok) {
                    float h1 = fmaf(g1[0], w0, fmaf(g1[1], w1, fmaf(g1[2], w2, fmaf(g1[3], w3, bb))));
                    p1.u[j] = f2bf(gelu(h1));
                } else p1.u[j] = 0;
            }
#pragma unroll
            for (int ni = 0; ni < 2; ++ni) {
                const int n = (2 * wid + ni) * 16 + lrow;
                bf16x8 b = *(const bf16x8*)(wB + n * 128 + kc * 32 + kq);
                acc[0][ni] = mfma16(p0.v, b, acc[0][ni]);
                acc[1][ni] = mfma16(p1.v, b, acc[1][ni]);
            }
        }
#pragma unroll
        for (int ni = 0; ni < 2; ++ni) {
            const int c = (2 * wid + ni) * 16 + lrow;
            const float bb = ch_fc2_b[c];
#pragma unroll
            for (int mt = 0; mt < 2; ++mt)
#pragma unroll
                for (int rr = 0; rr < 4; ++rr) {
                    const int v = mt * 16 + rrow + rr;
                    if (v < V) {
                        float val = acc[mt][ni][rr] + bb
                                  + tl_table[sTL[v] * C + c] + lane_table[sLT[v] * C + c];
                        s1[c * 72 + v] = f2bf(val);
                    }
                }
        }
    }
    // wave-local chain: phase A wrote rows 32*wid..+31 of s1; phase B reads the same stripe.

    // ==== Phase B: expand fc1 (K=32 padded), in-place gelu into s1[c*72 + t]
    {
        bf16x8 af[2];
#pragma unroll
        for (int mt = 0; mt < 2; ++mt) {
            const int m = 32 * wid + mt * 16 + lrow;
            af[mt] = *(const bf16x8*)(s1 + m * 72 + kq);
        }
        floatx4 acc[2][4];
#pragma unroll
        for (int mt = 0; mt < 2; ++mt)
#pragma unroll
            for (int nt = 0; nt < 4; ++nt) acc[mt][nt] = {0.f, 0.f, 0.f, 0.f};
        const unsigned short* wB = ws + WS_TOKFC1;
#pragma unroll
        for (int nt = 0; nt < 4; ++nt) {
            const int n = nt * 16 + lrow;
            bf16x8 b = *(const bf16x8*)(wB + n * 32 + kq);
            acc[0][nt] = mfma16(af[0], b, acc[0][nt]);
            acc[1][nt] = mfma16(af[1], b, acc[1][nt]);
        }
#pragma unroll
        for (int nt = 0; nt < 4; ++nt) {
            const int t = nt * 16 + lrow;
            const float bb = tok_fc1_b[t];
#pragma unroll
            for (int mt = 0; mt < 2; ++mt)
#pragma unroll
                for (int rr = 0; rr < 4; ++rr) {
                    const int m = 32 * wid + mt * 16 + rrow + rr;
                    s1[m * 72 + t] = f2bf(gelu(acc[mt][nt][rr] + bb));
                }
        }
    }
    __syncthreads();   // phase C reads s1 rows across all waves

    // ==== residual in registers (8 floatx4 = 32 fp32) ====
    floatx4 R[8];
#pragma unroll
    for (int nt = 0; nt < 8; ++nt) R[nt] = {0.f, 0.f, 0.f, 0.f};

    // Phase C: expand fc2 (K=64), swapped orientation -> R directly
    tok_fc2_to_R(s1, ws + WS_TOKFC2, tok_fc2_b, R, wid, lrow, kq, rrow);

    // ==== Mixer blocks ====
#pragma unroll 1
    for (int blk = 0; blk < DEPTH; ++blk) {
        __syncthreads();   // prior cross-wave s1 reads done before ln1 overwrites
        ln_reg(R, bn1w + blk * C, bn1b + blk * C, s1, wid, lrow, rrow, true);
        __syncthreads();   // ln1 writes (all threads scatter) visible
        tok_fc1_gelu(s1, ws + WS_BTOK1 + blk * 4096, btok1b + blk * T, wid, lrow, kq, rrow);
        __syncthreads();   // tok_fc1 wave-local writes visible (tok_fc2 reads all rows)
        tok_fc2_to_R(s1, ws + WS_BTOK2 + blk * 4096, btok2b + blk * T, R, wid, lrow, kq, rrow);
        __syncthreads();   // tok_fc2 cross-wave reads done before ln2 overwrites
        ln_reg(R, bn2w + blk * C, bn2b + blk * C, s1, wid, lrow, rrow, false);
        // ln2 writes rows [16w,16w+16) (wave-local); ch chain stays wave-local:
        ch_fc1_gelu(s1, ws + WS_BCH1 + blk * 16384, bch1b + blk * C, wid, lrow, kq, rrow);
        ch_fc2_to_R(s1, ws + WS_BCH2 + blk * 16384, bch2b + blk * C, R, wid, lrow, kq, rrow);
    }
    __syncthreads();   // all ch_fc2 reads done before s1 reuse as pool buffer

    // ==== mean over tokens (from R) + final LN + head ====
    {
        float* P = (float*)s1;               // [4][128] fp32 partials
        float snt[8];
#pragma unroll
        for (int nt = 0; nt < 8; ++nt)
            snt[nt] = (R[nt][0] + R[nt][1]) + (R[nt][2] + R[nt][3]);
#pragma unroll
        for (int nt = 0; nt < 8; ++nt) {
            snt[nt] += __shfl_xor(snt[nt], 16);
            snt[nt] += __shfl_xor(snt[nt], 32);
        }
        if (lane < 16) {
#pragma unroll
            for (int nt = 0; nt < 8; ++nt)
                P[wid * 128 + 16 * nt + lane] = snt[nt];
        }
    }
    __syncthreads();
    float fm = 0.f;
    {
        const float* P = (const float*)s1;
        if (tid < C) {
            fm = (P[tid] + P[128 + tid] + P[256 + tid] + P[384 + tid]) * (1.f / 64.f);
            sVec[tid] = fm;
        }
    }
    __syncthreads();
    {
        float s = 0.f, q = 0.f;
#pragma unroll
        for (int c = 0; c < C; c += 4) {
            float4 v = *(const float4*)(sVec + c);
            s += (v.x + v.y) + (v.z + v.w);
            q += v.x * v.x + v.y * v.y + v.z * v.z + v.w * v.w;
        }
        __syncthreads();
        const float m = s * (1.f / 128.f);
        const float rs = rsqrtf(q * (1.f / 128.f) - m * m + 1e-5f);
        if (tid < C) sVec[tid] = (fm - m) * rs * norm_w[tid] + norm_b[tid];
    }
    __syncthreads();

    if (tid < HDIM) {
        float a0 = 0.f, a1 = 0.f, a2 = 0.f, a3 = 0.f;
#pragma unroll 4
        for (int c = 0; c < C; c += 4) {
            float4 sv = *(const float4*)(sVec + c);
            a0 = fmaf(sv.x, emb1w[(c + 0) * HDIM + tid], a0);
            a1 = fmaf(sv.y, emb1w[(c + 1) * HDIM + tid], a1);
            a2 = fmaf(sv.z, emb1w[(c + 2) * HDIM + tid], a2);
            a3 = fmaf(sv.w, emb1w[(c + 3) * HDIM + tid], a3);
        }
        sVec[C + tid] = gelu(((a0 + a1) + (a2 + a3)) + emb1b[tid]);
    }
    __syncthreads();
    if (tid < HDIM) {
        float a0 = 0.f, a1 = 0.f, a2 = 0.f, a3 = 0.f;
#pragma unroll 4
        for (int j = 0; j < HDIM; j += 4) {
            float4 sv = *(const float4*)(sVec + C + j);
            a0 = fmaf(sv.x, emb2w[(j + 0) * HDIM + tid], a0);
            a1 = fmaf(sv.y, emb2w[(j + 1) * HDIM + tid], a1);
            a2 = fmaf(sv.z, emb2w[(j + 2) * HDIM + tid], a2);
            a3 = fmaf(sv.w, emb2w[(j + 3) * HDIM + tid], a3);
        }
        outp[(size_t)r * HDIM + tid] = (((a0 + a1) + (a2 + a3)) + emb2b[tid]) * sValidF;
    }
}

// ================= fallback scalar kernel (R1 version) =================
template<int K, int LDA, int N>
__device__ __forceinline__ void gemm_bf(const unsigned short* __restrict__ A,
                                        const float* __restrict__ W,
                                        float acc[4][8])
{
#pragma unroll 2
    for (int k = 0; k < K; k += 4) {
        float a[4][4];
#pragma unroll
        for (int i = 0; i < 4; ++i) {
            ushort4 raw = *(const ushort4*)(A + i * LDA + k);
            a[i][0] = bf2f(raw.x); a[i][1] = bf2f(raw.y);
            a[i][2] = bf2f(raw.z); a[i][3] = bf2f(raw.w);
        }
#pragma unroll
        for (int kk = 0; kk < 4; ++kk) {
            const float* wr = W + (k + kk) * N;
            float4 w0 = *(const float4*)(wr);
            float4 w1 = *(const float4*)(wr + 4);
#pragma unroll
            for (int i = 0; i < 4; ++i) {
                acc[i][0] = fmaf(a[i][kk], w0.x, acc[i][0]);
                acc[i][1] = fmaf(a[i][kk], w0.y, acc[i][1]);
                acc[i][2] = fmaf(a[i][kk], w0.z, acc[i][2]);
                acc[i][3] = fmaf(a[i][kk], w0.w, acc[i][3]);
                acc[i][4] = fmaf(a[i][kk], w1.x, acc[i][4]);
                acc[i][5] = fmaf(a[i][kk], w1.y, acc[i][5]);
                acc[i][6] = fmaf(a[i][kk], w1.z, acc[i][6]);
                acc[i][7] = fmaf(a[i][kk], w1.w, acc[i][7]);
            }
        }
    }
}

template<int K, int LDA, int N>
__device__ __forceinline__ void gemm_f32(const float* __restrict__ A,
                                         const float* __restrict__ W,
                                         float acc[4][8])
{
#pragma unroll
    for (int k = 0; k < K; k += 4) {
        float a[4][4];
#pragma unroll
        for (int i = 0; i < 4; ++i) {
            float4 v = *(const float4*)(A + i * LDA + k);
            a[i][0] = v.x; a[i][1] = v.y; a[i][2] = v.z; a[i][3] = v.w;
        }
#pragma unroll
        for (int kk = 0; kk < 4; ++kk) {
            const float* wr = W + (k + kk) * N;
            float4 w0 = *(const float4*)(wr);
            float4 w1 = *(const float4*)(wr + 4);
#pragma unroll
            for (int i = 0; i < 4; ++i) {
                acc[i][0] = fmaf(a[i][kk], w0.x, acc[i][0]);
                acc[i][1] = fmaf(a[i][kk], w0.y, acc[i][1]);
                acc[i][2] = fmaf(a[i][kk], w0.z, acc[i][2]);
                acc[i][3] = fmaf(a[i][kk], w0.w, acc[i][3]);
                acc[i][4] = fmaf(a[i][kk], w1.x, acc[i][4]);
                acc[i][5] = fmaf(a[i][kk], w1.y, acc[i][5]);
                acc[i][6] = fmaf(a[i][kk], w1.z, acc[i][6]);
                acc[i][7] = fmaf(a[i][kk], w1.w, acc[i][7]);
            }
        }
    }
}

__global__ __launch_bounds__(256, 3)
void lanefusion_scalar(
    const float* __restrict__ x,
    const float* __restrict__ tl_table, const float* __restrict__ lane_table,
    const float* __restrict__ ch_fc1_w, const float* __restrict__ ch_fc1_b,
    const float* __restrict__ ch_fc2_w, const float* __restrict__ ch_fc2_b,
    const float* __restrict__ tok_fc1_w, const float* __restrict__ tok_fc1_b,
    const float* __restrict__ tok_fc2_w, const float* __restrict__ tok_fc2_b,
    const float* __restrict__ bn1w, const float* __restrict__ bn1b,
    const float* __restrict__ btok1w, const float* __restrict__ btok1b,
    const float* __restrict__ btok2w, const float* __restrict__ btok2b,
    const float* __restrict__ bn2w, const float* __restrict__ bn2b,
    const float* __restrict__ bch1w, const float* __restrict__ bch1b,
    const float* __restrict__ bch2w, const float* __restrict__ bch2b,
    const float* __restrict__ norm_w, const float* __restrict__ norm_b,
    const float* __restrict__ emb1w, const float* __restrict__ emb1b,
    const float* __restrict__ emb2w, const float* __restrict__ emb2b,
    float* __restrict__ out)
{
    __shared__ float sF[T * 132];
    __shared__ unsigned short sA[8704];
    __shared__ float sVec[320];
    __shared__ int sTL[V], sLT[V], sMaskV[V];
    __shared__ float sValidF;

    const int tid = threadIdx.x;
    const int r = blockIdx.x;

    float* outp  = out;
    float* maskp = out + (size_t)NROWS * HDIM;
    float* posp  = maskp + NROWS;

    float* sX = sVec;
    float* sG = sVec + 128;

    const float* xr = x + (size_t)r * (V * 5);
    if (tid < V * 5) sX[tid] = xr[tid];
    __syncthreads();

    if (tid < V) {
        float x0 = sX[tid * 5 + 0], x1 = sX[tid * 5 + 1], hd = sX[tid * 5 + 2];
        float chv = cosf(hd), shv = sinf(hd);
        sG[tid * 4 + 0] = x0; sG[tid * 4 + 1] = x1;
        sG[tid * 4 + 2] = chv; sG[tid * 4 + 3] = shv;
        int nz = (x0 != 0.f) + (x1 != 0.f) + (chv != 0.f) + (shv != 0.f);
        sMaskV[tid] = (nz == 0);
        int tl = (int)sX[tid * 5 + 3]; tl = tl < 0 ? 0 : (tl > 8 ? 8 : tl);
        int lt = (int)sX[tid * 5 + 4]; lt = lt < 0 ? 0 : (lt > 19 ? 19 : lt);
        sTL[tid] = tl; sLT[tid] = lt;
    }
    __syncthreads();

    if (tid == 0) {
        int mp = 1;
        for (int v = 0; v < V; ++v) mp &= sMaskV[v];
        sValidF = mp ? 0.f : 1.f;
        maskp[r] = mp ? 1.f : 0.f;
        posp[(size_t)r * 5 + 0] = sX[50];
        posp[(size_t)r * 5 + 1] = sX[51];
        posp[(size_t)r * 5 + 2] = sX[52];
        posp[(size_t)r * 5 + 3] = sX[53] * (1.f / 8.f);
        posp[(size_t)r * 5 + 4] = sX[54] * (1.f / 19.f);
    }

    if (tid < 160) {
        const int v = tid >> 3, c0 = (tid & 7) * 16;
        const float g0 = sG[v * 4 + 0], g1 = sG[v * 4 + 1],
                    g2 = sG[v * 4 + 2], g3 = sG[v * 4 + 3];
#pragma unroll
        for (int j = 0; j < 16; ++j) {
            const int c = c0 + j;
            float s = ch_fc1_b[c];
            s = fmaf(g0, ch_fc1_w[0 * C + c], s);
            s = fmaf(g1, ch_fc1_w[1 * C + c], s);
            s = fmaf(g2, ch_fc1_w[2 * C + c], s);
            s = fmaf(g3, ch_fc1_w[3 * C + c], s);
            sA[v * 132 + c] = f2bf(gelu(s));
        }
    }
    __syncthreads();

    if (tid < 160) {
        const int v = tid >> 3, c0 = (tid & 7) * 16;
        float acc[16];
#pragma unroll
        for (int j = 0; j < 16; ++j) acc[j] = 0.f;
        const unsigned short* Arow = sA + v * 132;
        for (int k = 0; k < C; k += 4) {
            ushort4 raw = *(const ushort4*)(Arow + k);
            float a4[4] = { bf2f(raw.x), bf2f(raw.y), bf2f(raw.z), bf2f(raw.w) };
#pragma unroll
            for (int kk = 0; kk < 4; ++kk) {
                const float* wr = ch_fc2_w + (k + kk) * C + c0;
                float4 w0 = *(const float4*)(wr);
                float4 w1 = *(const float4*)(wr + 4);
                float4 w2 = *(const float4*)(wr + 8);
                float4 w3 = *(const float4*)(wr + 12);
                acc[0]  = fmaf(a4[kk], w0.x, acc[0]);  acc[1]  = fmaf(a4[kk], w0.y, acc[1]);
                acc[2]  = fmaf(a4[kk], w0.z, acc[2]);  acc[3]  = fmaf(a4[kk], w0.w, acc[3]);
                acc[4]  = fmaf(a4[kk], w1.x, acc[4]);  acc[5]  = fmaf(a4[kk], w1.y, acc[5]);
                acc[6]  = fmaf(a4[kk], w1.z, acc[6]);  acc[7]  = fmaf(a4[kk], w1.w, acc[7]);
                acc[8]  = fmaf(a4[kk], w2.x, acc[8]);  acc[9]  = fmaf(a4[kk], w2.y, acc[9]);
                acc[10] = fmaf(a4[kk], w2.z, acc[10]); acc[11] = fmaf(a4[kk], w2.w, acc[11]);
                acc[12] = fmaf(a4[kk], w3.x, acc[12]); acc[13] = fmaf(a4[kk], w3.y, acc[13]);
                acc[14] = fmaf(a4[kk], w3.z, acc[14]); acc[15] = fmaf(a4[kk], w3.w, acc[15]);
            }
        }
        const int tl = sTL[v], lt = sLT[v];
#pragma unroll
        for (int j = 0; j < 16; ++j) {
            const int c = c0 + j;
            sF[c * 20 + v] = acc[j] + ch_fc2_b[c] + tl_table[tl * C + c] + lane_table[lt * C + c];
        }
    }
    __syncthreads();

    {
        const int r0 = (tid >> 3) * 4, c0 = (tid & 7) * 8;
        float acc[4][8] = {};
        gemm_f32<20, 20, 64>(sF + r0 * 20, tok_fc1_w + c0, acc);
#pragma unroll
        for (int i = 0; i < 4; ++i)
#pragma unroll
            for (int j = 0; j < 8; ++j)
                sA[(r0 + i) * 68 + c0 + j] = f2bf(gelu(acc[i][j] + tok_fc1_b[c0 + j]));
    }
    __syncthreads();

    {
        const int r0 = (tid >> 3) * 4, c0 = (tid & 7) * 8;
        float acc[4][8] = {};
        gemm_bf<64, 68, 64>(sA + r0 * 68, tok_fc2_w + c0, acc);
#pragma unroll
        for (int i = 0; i < 4; ++i)
#pragma unroll
            for (int j = 0; j < 8; ++j)
                sF[(c0 + j) * 132 + (r0 + i)] = acc[i][j] + tok_fc2_b[c0 + j];
    }
    __syncthreads();

    for (int blk = 0; blk < DEPTH; ++blk) {
        layer_norm_to(sF, sA, bn1w + blk * C, bn1b + blk * C, tid, true, 68);
        __syncthreads();
        {
            const int r0 = (tid >> 3) * 4, c0 = (tid & 7) * 8;
            float acc[4][8] = {};
            gemm_bf<64, 68, 64>(sA + r0 * 68, btok1w + blk * T * T + c0, acc);
#pragma unroll
            for (int i = 0; i < 4; ++i)
#pragma unroll
                for (int j = 0; j < 8; ++j)
                    acc[i][j] = gelu(acc[i][j] + btok1b[blk * T + c0 + j]);
            __syncthreads();
#pragma unroll
            for (int i = 0; i < 4; ++i)
#pragma unroll
                for (int j = 0; j < 8; ++j)
                    sA[(r0 + i) * 68 + c0 + j] = f2bf(acc[i][j]);
        }
        __syncthreads();
        {
            const int r0 = (tid >> 3) * 4, c0 = (tid & 7) * 8;
            float acc[4][8] = {};
            gemm_bf<64, 68, 64>(sA + r0 * 68, btok2w + blk * T * T + c0, acc);
#pragma unroll
            for (int i = 0; i < 4; ++i)
#pragma unroll
                for (int j = 0; j < 8; ++j)
                    sF[(c0 + j) * 132 + (r0 + i)] += acc[i][j] + btok2b[blk * T + c0 + j];
        }
        __syncthreads();

        layer_norm_to(sF, sA, bn2w + blk * C, bn2b + blk * C, tid, false, 132);
        __syncthreads();
        {
            const int r0 = (tid >> 4) * 4, c0 = (tid & 15) * 8;
            float acc[4][8] = {};
            gemm_bf<128, 132, 128>(sA + r0 * 132, bch1w + blk * C * C + c0, acc);
#pragma unroll
            for (int i = 0; i < 4; ++i)
#pragma unroll
                for (int j = 0; j < 8; ++j)
                    acc[i][j] = gelu(acc[i][j] + bch1b[blk * C + c0 + j]);
            __syncthreads();
#pragma unroll
            for (int i = 0; i < 4; ++i)
#pragma unroll
                for (int j = 0; j < 8; ++j)
                    sA[(r0 + i) * 132 + c0 + j] = f2bf(acc[i][j]);
        }
        __syncthreads();
        {
            const int r0 = (tid >> 4) * 4, c0 = (tid & 15) * 8;
            float acc[4][8] = {};
            gemm_bf<128, 132, 128>(sA + r0 * 132, bch2w + blk * C * C + c0, acc);
#pragma unroll
            for (int i = 0; i < 4; ++i)
#pragma unroll
                for (int j = 0; j < 8; ++j)
                    sF[(r0 + i) * 132 + c0 + j] += acc[i][j] + bch2b[blk * C + c0 + j];
        }
        __syncthreads();
    }

    float fm = 0.f;
    if (tid < C) {
#pragma unroll 8
        for (int t = 0; t < T; ++t) fm += sF[t * 132 + tid];
        fm *= (1.f / 64.f);
        sVec[tid] = fm;
    }
    __syncthreads();
    {
        float s = 0.f, q = 0.f;
        for (int c = 0; c < C; ++c) { float v = sVec[c]; s += v; q += v * v; }
        __syncthreads();
        const float m = s * (1.f / 128.f);
        const float rs = rsqrtf(q * (1.f / 128.f) - m * m + 1e-5f);
        if (tid < C) sVec[tid] = (fm - m) * rs * norm_w[tid] + norm_b[tid];
    }
    __syncthreads();

    if (tid < HDIM) {
        float v1 = emb1b[tid];
        for (int c = 0; c < C; ++c) v1 = fmaf(sVec[c], emb1w[c * HDIM + tid], v1);
        sVec[C + tid] = gelu(v1);
    }
    __syncthreads();
    if (tid < HDIM) {
        float v2 = emb2b[tid];
        for (int j = 0; j < HDIM; ++j) v2 = fmaf(sVec[C + j], emb2w[j * HDIM + tid], v2);
        outp[(size_t)r * HDIM + tid] = v2 * sValidF;
    }
}

extern "C" void kernel_launch(void* const* d_in, const int* in_sizes, int n_in,
                              void* d_out, int out_size, void* d_ws, size_t ws_size,
                              hipStream_t stream) {
    (void)in_sizes; (void)n_in; (void)out_size;
    if (ws_size >= (size_t)WS_TOTAL * 2) {
        prep_weights<<<dim3((WS_TOTAL + 255) / 256), dim3(256), 0, stream>>>(
            (const float*)d_in[7],  // tok_fc1_w
            (const float*)d_in[9],  // tok_fc2_w
            (const float*)d_in[13], // blk_tok_fc1_w
            (const float*)d_in[15], // blk_tok_fc2_w
            (const float*)d_in[5],  // ch_fc2_w
            (const float*)d_in[19], // blk_ch_fc1_w
            (const float*)d_in[21], // blk_ch_fc2_w
            (unsigned short*)d_ws);
        lanefusion_mfma<<<dim3(NROWS), dim3(256), 0, stream>>>(
            (const float*)d_in[0],  (const float*)d_in[1],  (const float*)d_in[2],
            (const float*)d_in[3],  (const float*)d_in[4],
            (const float*)d_in[6],
            (const float*)d_in[8],  (const float*)d_in[10],
            (const float*)d_in[11], (const float*)d_in[12],
            (const float*)d_in[14], (const float*)d_in[16],
            (const float*)d_in[17], (const float*)d_in[18],
            (const float*)d_in[20], (const float*)d_in[22],
            (const float*)d_in[23], (const float*)d_in[24],
            (const float*)d_in[25], (const float*)d_in[26],
            (const float*)d_in[27], (const float*)d_in[28],
            (const unsigned short*)d_ws,
            (float*)d_out);
    } else {
        lanefusion_scalar<<<dim3(NROWS), dim3(256), 0, stream>>>(
            (const float*)d_in[0],  (const float*)d_in[1],  (const float*)d_in[2],
            (const float*)d_in[3],  (const float*)d_in[4],  (const float*)d_in[5],
            (const float*)d_in[6],  (const float*)d_in[7],  (const float*)d_in[8],
            (const float*)d_in[9],  (const float*)d_in[10], (const float*)d_in[11],
            (const float*)d_in[12], (const float*)d_in[13], (const float*)d_in[14],
            (const float*)d_in[15], (const float*)d_in[16], (const float*)d_in[17],
            (const float*)d_in[18], (const float*)d_in[19], (const float*)d_in[20],
            (const float*)d_in[21], (const float*)d_in[22], (const float*)d_in[23],
            (const float*)d_in[24], (const float*)d_in[25], (const float*)d_in[26],
            (const float*)d_in[27], (const float*)d_in[28],
            (float*)d_out);
    }
}

// Round 11
// 1117.933 us; speedup vs baseline: 1.1155x; 1.0025x over previous
//
#include <hip/hip_runtime.h>
#include <hip/hip_bf16.h>

#define NROWS 8192
#define V 20
#define C 128
#define T 64
#define HDIM 192
#define DEPTH 3

typedef __attribute__((ext_vector_type(8))) short bf16x8;
typedef __attribute__((ext_vector_type(4))) float floatx4;

// ---- ws segment offsets (bf16 elements), all W^T [N][K] ----
#define WS_TOKFC1 0        // [64][32]  (k>=20 zero-padded)
#define WS_TOKFC2 2048     // [64][64]
#define WS_BTOK1  6144     // [3][64][64]
#define WS_BTOK2  18432    // [3][64][64]
#define WS_CHFC2  30720    // [128][128]
#define WS_BCH1   47104    // [3][128][128]
#define WS_BCH2   96256    // [3][128][128]
#define WS_TOTAL  145408   // elements -> 290816 bytes

// ---------- helpers ----------
__device__ __forceinline__ float bf2f(unsigned short u) {
    union { unsigned int i; float f; } c; c.i = ((unsigned int)u) << 16; return c.f;
}
// Native RNE cast: lets the compiler emit v_cvt_pk_bf16_f32 (1 inst, pairable)
// instead of the 5-op manual round-to-nearest-even bit sequence.
__device__ __forceinline__ unsigned short f2bf(float f) {
    union { __hip_bfloat16 b; unsigned short u; } c;
    c.b = __float2bfloat16(f);
    return c.u;
}
// Fast GELU (tanh form): x * sigmoid(1.59576912*(x + 0.044715 x^3)).
__device__ __forceinline__ float gelu(float x) {
    float u = x * x;
    float p = fmaf(u, 0.044715f, 1.0f);
    float arg = x * p * -2.3022042f;   // -1.59576912 * log2(e)
    float e = __builtin_amdgcn_exp2f(arg);
    return x * __builtin_amdgcn_rcpf(1.0f + e);
}
__device__ __forceinline__ floatx4 mfma16(bf16x8 a, bf16x8 b, floatx4 c) {
    return __builtin_amdgcn_mfma_f32_16x16x32_bf16(a, b, c, 0, 0, 0);
}

// ================== register-residual building blocks (lean-liveness) ======
// Residual ownership: thread (wid, lane) owns token t = 16*wid + rrow + rr,
// channel c = 16*nt + lrow  ->  R[nt][rr], 8 floatx4 = 32 fp32 per thread.
// BOTH fc2 GEMMs are oriented so their MFMA C/D layout == R's layout, so R
// itself is the MFMA accumulator (no separate acc, no LDS redistribution).

// LayerNorm from registers; writes normalized bf16 to s1.
// transposed=true  -> s1[c*72 + t]   (token-GEMM staging)
// transposed=false -> s1[t*136 + c]  (channel-GEMM staging)
__device__ __forceinline__ void ln_reg(const floatx4 (&R)[8],
                                       const float* __restrict__ w,
                                       const float* __restrict__ b,
                                       unsigned short* __restrict__ s1,
                                       int wid, int lrow, int rrow, bool transposed)
{
    float s[4], q[4];
#pragma unroll
    for (int rr = 0; rr < 4; ++rr) {
        float ss = 0.f, qq = 0.f;
#pragma unroll
        for (int nt = 0; nt < 8; ++nt) { float v = R[nt][rr]; ss += v; qq += v * v; }
        s[rr] = ss; q[rr] = qq;
    }
    // per-token reduce across the 16 lanes sharing a token (lanes differ in lrow)
#pragma unroll
    for (int rr = 0; rr < 4; ++rr) {
        s[rr] += __shfl_xor(s[rr], 1);  q[rr] += __shfl_xor(q[rr], 1);
        s[rr] += __shfl_xor(s[rr], 2);  q[rr] += __shfl_xor(q[rr], 2);
        s[rr] += __shfl_xor(s[rr], 4);  q[rr] += __shfl_xor(q[rr], 4);
        s[rr] += __shfl_xor(s[rr], 8);  q[rr] += __shfl_xor(q[rr], 8);
    }
    float m[4], rs[4];
#pragma unroll
    for (int rr = 0; rr < 4; ++rr) {
        m[rr] = s[rr] * (1.f / 128.f);
        rs[rr] = rsqrtf(q[rr] * (1.f / 128.f) - m[rr] * m[rr] + 1e-5f);
    }
#pragma unroll
    for (int nt = 0; nt < 8; ++nt) {
        const int c = 16 * nt + lrow;
        const float wv = w[c], bv = b[c];
#pragma unroll
        for (int rr = 0; rr < 4; ++rr) {
            const int t = 16 * wid + rrow + rr;
            unsigned short o = f2bf((R[nt][rr] - m[rr]) * rs[rr] * wv + bv);
            if (transposed) s1[c * 72 + t] = o;
            else            s1[t * 136 + c] = o;
        }
    }
}

// token fc1 (K=64): A = s1 [c][t] wave stripe, gelu, in-place write.
// Split by mt so transient acc is only 4 floatx4 (16 regs) while R idles.
// In-place safe: mt=0 writes rows [32w,32w+16) before mt=1 reads [32w+16,32w+32).
__device__ __forceinline__ void tok_fc1_gelu(unsigned short* __restrict__ s1,
                                             const unsigned short* __restrict__ wB,
                                             const float* __restrict__ bias,
                                             int wid, int lrow, int kq, int rrow)
{
#pragma unroll
    for (int mt = 0; mt < 2; ++mt) {
        bf16x8 at[2];
#pragma unroll
        for (int kc = 0; kc < 2; ++kc)
            at[kc] = *(const bf16x8*)(s1 + (32 * wid + mt * 16 + lrow) * 72 + kc * 32 + kq);
        floatx4 acc[4];
#pragma unroll
        for (int nt = 0; nt < 4; ++nt) acc[nt] = {0.f, 0.f, 0.f, 0.f};
#pragma unroll
        for (int nt = 0; nt < 4; ++nt)
#pragma unroll
            for (int kc = 0; kc < 2; ++kc) {
                bf16x8 b = *(const bf16x8*)(wB + (nt * 16 + lrow) * 64 + kc * 32 + kq);
                acc[nt] = mfma16(at[kc], b, acc[nt]);
            }
#pragma unroll
        for (int nt = 0; nt < 4; ++nt) {
            const int t = nt * 16 + lrow;
            const float bb = bias[t];
#pragma unroll
            for (int rr = 0; rr < 4; ++rr)
                s1[(32 * wid + mt * 16 + rrow + rr) * 72 + t] = f2bf(gelu(acc[nt][rr] + bb));
        }
    }
}

// token fc2 (K=64), OPERAND-SWAPPED: D[m=t'][n=c] = W[t'][t] * X^T[c][t].
// Wave wid owns m-tile t' in [16w,16w+16); n spans all 8 c-tiles.
// D layout == R layout exactly -> R is the MFMA accumulator (seeded C-in).
// Reads s1 rows across ALL waves: caller must barrier before AND after.
__device__ __forceinline__ void tok_fc2_to_R(const unsigned short* __restrict__ s1,
                                             const unsigned short* __restrict__ wB,
                                             const float* __restrict__ bias,
                                             floatx4 (&R)[8],
                                             int wid, int lrow, int kq, int rrow)
{
    bf16x8 aw[2];
#pragma unroll
    for (int kc = 0; kc < 2; ++kc)
        aw[kc] = *(const bf16x8*)(wB + (16 * wid + lrow) * 64 + kc * 32 + kq);
    float bb[4];
#pragma unroll
    for (int rr = 0; rr < 4; ++rr) bb[rr] = bias[16 * wid + rrow + rr];
#pragma unroll
    for (int nt = 0; nt < 8; ++nt) {
        floatx4 acc = R[nt];
#pragma unroll
        for (int kc = 0; kc < 2; ++kc) {
            bf16x8 b = *(const bf16x8*)(s1 + (16 * nt + lrow) * 72 + kc * 32 + kq);
            acc = mfma16(aw[kc], b, acc);
        }
#pragma unroll
        for (int rr = 0; rr < 4; ++rr) acc[rr] += bb[rr];
        R[nt] = acc;
    }
}

// channel fc1 (K=128): A = s1 [t][c] wave rows, gelu, in-place.
// Split into 4 groups of 2 n-tiles: transient acc = 2 floatx4 (8 regs).
__device__ __forceinline__ void ch_fc1_gelu(unsigned short* __restrict__ s1,
                                            const unsigned short* __restrict__ wB,
                                            const float* __restrict__ bias,
                                            int wid, int lrow, int kq, int rrow)
{
    bf16x8 a2[4];
    const int m = 16 * wid + lrow;
#pragma unroll
    for (int kc = 0; kc < 4; ++kc)
        a2[kc] = *(const bf16x8*)(s1 + m * 136 + kc * 32 + kq);
#pragma unroll
    for (int g = 0; g < 4; ++g) {
        floatx4 acc[2];
#pragma unroll
        for (int i = 0; i < 2; ++i) acc[i] = {0.f, 0.f, 0.f, 0.f};
#pragma unroll
        for (int i = 0; i < 2; ++i) {
            const int n = (2 * g + i) * 16 + lrow;
#pragma unroll
            for (int kc = 0; kc < 4; ++kc) {
                bf16x8 b = *(const bf16x8*)(wB + n * 128 + kc * 32 + kq);
                acc[i] = mfma16(a2[kc], b, acc[i]);
            }
        }
#pragma unroll
        for (int i = 0; i < 2; ++i) {
            const int c = (2 * g + i) * 16 + lrow;
            const float bb = bias[c];
#pragma unroll
            for (int rr = 0; rr < 4; ++rr)
                s1[(16 * wid + rrow + rr) * 136 + c] = f2bf(gelu(acc[i][rr] + bb));
        }
    }
}

// channel fc2 (K=128): D[m=t][n=c] with R as seeded accumulator. Wave-local reads.
__device__ __forceinline__ void ch_fc2_to_R(const unsigned short* __restrict__ s1,
                                            const unsigned short* __restrict__ wB,
                                            const float* __restrict__ bias,
                                            floatx4 (&R)[8],
                                            int wid, int lrow, int kq, int rrow)
{
    bf16x8 a2[4];
    const int m = 16 * wid + lrow;
#pragma unroll
    for (int kc = 0; kc < 4; ++kc)
        a2[kc] = *(const bf16x8*)(s1 + m * 136 + kc * 32 + kq);
#pragma unroll
    for (int nt = 0; nt < 8; ++nt) {
        floatx4 acc = R[nt];
        const float bb = bias[16 * nt + lrow];
#pragma unroll
        for (int kc = 0; kc < 4; ++kc) {
            bf16x8 b = *(const bf16x8*)(wB + (16 * nt + lrow) * 128 + kc * 32 + kq);
            acc = mfma16(a2[kc], b, acc);
        }
#pragma unroll
        for (int rr = 0; rr < 4; ++rr) acc[rr] += bb;
        R[nt] = acc;
    }
}

// LN over C=128 per token; 4 threads/token (scalar-fallback kernel only).
__device__ __forceinline__ void layer_norm_to(const float* __restrict__ sF,
                                              unsigned short* __restrict__ sA,
                                              const float* __restrict__ w,
                                              const float* __restrict__ b,
                                              int tid, bool transposed, int strideOut)
{
    const int t = tid >> 2, part = tid & 3;
    const float* row = sF + t * 132 + part * 32;
    float s = 0.f, q = 0.f;
#pragma unroll
    for (int j = 0; j < 8; ++j) {
        float4 v = *(const float4*)(row + j * 4);
        s += (v.x + v.y) + (v.z + v.w);
        q += v.x * v.x + v.y * v.y + v.z * v.z + v.w * v.w;
    }
    s += __shfl_xor(s, 1); q += __shfl_xor(q, 1);
    s += __shfl_xor(s, 2); q += __shfl_xor(q, 2);
    const float m = s * (1.f / 128.f);
    const float rs = rsqrtf(q * (1.f / 128.f) - m * m + 1e-5f);
#pragma unroll
    for (int j = 0; j < 8; ++j) {
        float4 v = *(const float4*)(row + j * 4);
        const int c = part * 32 + j * 4;
        float4 wv = *(const float4*)(w + c);
        float4 bv = *(const float4*)(b + c);
        unsigned short o0 = f2bf((v.x - m) * rs * wv.x + bv.x);
        unsigned short o1 = f2bf((v.y - m) * rs * wv.y + bv.y);
        unsigned short o2 = f2bf((v.z - m) * rs * wv.z + bv.z);
        unsigned short o3 = f2bf((v.w - m) * rs * wv.w + bv.w);
        if (transposed) {
            sA[(c + 0) * strideOut + t] = o0;
            sA[(c + 1) * strideOut + t] = o1;
            sA[(c + 2) * strideOut + t] = o2;
            sA[(c + 3) * strideOut + t] = o3;
        } else {
            ushort4 pk; pk.x = o0; pk.y = o1; pk.z = o2; pk.w = o3;
            *(ushort4*)(sA + t * strideOut + c) = pk;
        }
    }
}

// ---------- prep: fp32 [K][N] -> bf16 W^T [N][K] in ws ----------
__global__ void prep_weights(const float* __restrict__ tokfc1,
                             const float* __restrict__ tokfc2,
                             const float* __restrict__ btok1,
                             const float* __restrict__ btok2,
                             const float* __restrict__ chfc2,
                             const float* __restrict__ bch1,
                             const float* __restrict__ bch2,
                             unsigned short* __restrict__ ws)
{
    int idx = blockIdx.x * 256 + threadIdx.x;
    if (idx >= WS_TOTAL) return;
    if (idx < 2048) {                                   // tokfc1T [64][32]
        int n = idx >> 5, k = idx & 31;
        ws[WS_TOKFC1 + idx] = (k < V) ? f2bf(tokfc1[k * 64 + n]) : 0;
        return;
    }
    idx -= 2048;
    if (idx < 4096) {                                   // tokfc2T [64][64]
        int n = idx >> 6, k = idx & 63;
        ws[WS_TOKFC2 + idx] = f2bf(tokfc2[k * 64 + n]);
        return;
    }
    idx -= 4096;
    if (idx < 12288) {                                  // btok1T [3][64][64]
        int d = idx >> 12, rem = idx & 4095, n = rem >> 6, k = rem & 63;
        ws[WS_BTOK1 + idx] = f2bf(btok1[d * 4096 + k * 64 + n]);
        return;
    }
    idx -= 12288;
    if (idx < 12288) {                                  // btok2T [3][64][64]
        int d = idx >> 12, rem = idx & 4095, n = rem >> 6, k = rem & 63;
        ws[WS_BTOK2 + idx] = f2bf(btok2[d * 4096 + k * 64 + n]);
        return;
    }
    idx -= 12288;
    if (idx < 16384) {                                  // chfc2T [128][128]
        int n = idx >> 7, k = idx & 127;
        ws[WS_CHFC2 + idx] = f2bf(chfc2[k * 128 + n]);
        return;
    }
    idx -= 16384;
    if (idx < 49152) {                                  // bch1T [3][128][128]
        int d = idx >> 14, rem = idx & 16383, n = rem >> 7, k = rem & 127;
        ws[WS_BCH1 + idx] = f2bf(bch1[d * 16384 + k * 128 + n]);
        return;
    }
    idx -= 49152;
    {                                                   // bch2T [3][128][128]
        int d = idx >> 14, rem = idx & 16383, n = rem >> 7, k = rem & 127;
        ws[WS_BCH2 + idx] = f2bf(bch2[d * 16384 + k * 128 + n]);
    }
}

// ---------- MFMA main kernel ----------
// waves_per_eu(4): min 4 waves/EU -> unified (VGPR+AGPR) budget 128/thread.
// R10 measured: arch=64, occ 45.6% (4 blocks/CU), marginal spill ~2.3 KB/block
// (WRITE_SIZE 26 MB, ~1 us) -- acceptable. Register/occupancy ledger validated.
__global__ __launch_bounds__(256) __attribute__((amdgpu_waves_per_eu(4)))
void lanefusion_mfma(
    const float* __restrict__ x,
    const float* __restrict__ tl_table, const float* __restrict__ lane_table,
    const float* __restrict__ ch_fc1_w, const float* __restrict__ ch_fc1_b,
    const float* __restrict__ ch_fc2_b,
    const float* __restrict__ tok_fc1_b, const float* __restrict__ tok_fc2_b,
    const float* __restrict__ bn1w, const float* __restrict__ bn1b,
    const float* __restrict__ btok1b, const float* __restrict__ btok2b,
    const float* __restrict__ bn2w, const float* __restrict__ bn2b,
    const float* __restrict__ bch1b, const float* __restrict__ bch2b,
    const float* __restrict__ norm_w, const float* __restrict__ norm_b,
    const float* __restrict__ emb1w, const float* __restrict__ emb1b,
    const float* __restrict__ emb2w, const float* __restrict__ emb2b,
    const unsigned short* __restrict__ ws,
    float* __restrict__ out)
{
    // s1 views: bf16 [128][72] (token staging) / bf16 [64][136] (channel staging)
    //         / fp32 [4][128] (pool partials)
    __shared__ unsigned short s1[128 * 72];  // 18432 B
    __shared__ float sVec[320];
    __shared__ int sTL[V], sLT[V], sMaskV[V];
    __shared__ float sValidF;

    const int tid = threadIdx.x;
    const int r = blockIdx.x;
    const int lane = tid & 63, wid = tid >> 6;
    const int lrow = lane & 15;
    const int kq = (lane >> 4) * 8;           // k-offset within a 32-chunk
    const int rrow = (lane >> 4) * 4;         // D row base within 16-tile

    float* outp  = out;
    float* maskp = out + (size_t)NROWS * HDIM;
    float* posp  = maskp + NROWS;

    float* sX = sVec;        // [100]
    float* sG = sVec + 128;  // [80]

    // zero s1 entirely: phase B reads k in [20,32) which is never written
    // (zero-padded K); uninitialized LDS there can be NaN-patterned -> NaN*0=NaN.
    {
        uint4* p = (uint4*)s1;               // 18432 B = 1152 uint4
        uint4 z; z.x = z.y = z.z = z.w = 0u;
        for (int i = tid; i < 1152; i += 256) p[i] = z;
    }

    const float* xr = x + (size_t)r * (V * 5);
    if (tid < V * 5) sX[tid] = xr[tid];
    __syncthreads();

    if (tid < V) {
        float x0 = sX[tid * 5 + 0], x1 = sX[tid * 5 + 1], hd = sX[tid * 5 + 2];
        float chv = cosf(hd), shv = sinf(hd);
        sG[tid * 4 + 0] = x0; sG[tid * 4 + 1] = x1;
        sG[tid * 4 + 2] = chv; sG[tid * 4 + 3] = shv;
        int nz = (x0 != 0.f) + (x1 != 0.f) + (chv != 0.f) + (shv != 0.f);
        sMaskV[tid] = (nz == 0);
        int tl = (int)sX[tid * 5 + 3]; tl = tl < 0 ? 0 : (tl > 8 ? 8 : tl);
        int lt = (int)sX[tid * 5 + 4]; lt = lt < 0 ? 0 : (lt > 19 ? 19 : lt);
        sTL[tid] = tl; sLT[tid] = lt;
    }
    __syncthreads();

    if (tid == 0) {
        int mp = 1;
        for (int v = 0; v < V; ++v) mp &= sMaskV[v];
        sValidF = mp ? 0.f : 1.f;
        maskp[r] = mp ? 1.f : 0.f;
        posp[(size_t)r * 5 + 0] = sX[50];
        posp[(size_t)r * 5 + 1] = sX[51];
        posp[(size_t)r * 5 + 2] = sX[52];
        posp[(size_t)r * 5 + 3] = sX[53] * (1.f / 8.f);
        posp[(size_t)r * 5 + 4] = sX[54] * (1.f / 19.f);
    }

    // ==== Phase A: h0 = gelu(g@W1+b1) in regs; f0 = h0@chfc2 (+b+tables) -> s1[c*72+v]
    // Per-kc chunks (unroll 1) to bound liveness: pack 1 frag-pair, 2 B-loads,
    // 4 MFMA, release. Accumulation order per acc unchanged (kc ascending).
    {
        float g0[4], g1[4];
        const bool v1ok = (lrow < 4);
        const int v0 = lrow, v1 = 16 + lrow;
#pragma unroll
        for (int i = 0; i < 4; ++i) {
            g0[i] = sG[v0 * 4 + i];
            g1[i] = v1ok ? sG[v1 * 4 + i] : 0.f;
        }
        floatx4 acc[2][2];
#pragma unroll
        for (int mt = 0; mt < 2; ++mt)
#pragma unroll
            for (int ni = 0; ni < 2; ++ni) acc[mt][ni] = {0.f, 0.f, 0.f, 0.f};
        const unsigned short* wB = ws + WS_CHFC2;
#pragma unroll 1
        for (int kc = 0; kc < 4; ++kc) {
            union { unsigned short u[8]; bf16x8 v; } p0, p1;
            const int kb = kc * 32 + kq;
#pragma unroll
            for (int j = 0; j < 8; ++j) {
                const float w0 = ch_fc1_w[0 * C + kb + j];
                const float w1 = ch_fc1_w[1 * C + kb + j];
                const float w2 = ch_fc1_w[2 * C + kb + j];
                const float w3 = ch_fc1_w[3 * C + kb + j];
                const float bb = ch_fc1_b[kb + j];
                float h0 = fmaf(g0[0], w0, fmaf(g0[1], w1, fmaf(g0[2], w2, fmaf(g0[3], w3, bb))));
                p0.u[j] = f2bf(gelu(h0));
                if (v1ok) {
                    float h1 = fmaf(g1[0], w0, fmaf(g1[1], w1, fmaf(g1[2], w2, fmaf(g1[3], w3, bb))));
                    p1.u[j] = f2bf(gelu(h1));
                } else p1.u[j] = 0;
            }
#pragma unroll
            for (int ni = 0; ni < 2; ++ni) {
                const int n = (2 * wid + ni) * 16 + lrow;
                bf16x8 b = *(const bf16x8*)(wB + n * 128 + kc * 32 + kq);
                acc[0][ni] = mfma16(p0.v, b, acc[0][ni]);
                acc[1][ni] = mfma16(p1.v, b, acc[1][ni]);
            }
        }
#pragma unroll
        for (int ni = 0; ni < 2; ++ni) {
            const int c = (2 * wid + ni) * 16 + lrow;
            const float bb = ch_fc2_b[c];
#pragma unroll
            for (int mt = 0; mt < 2; ++mt)
#pragma unroll
                for (int rr = 0; rr < 4; ++rr) {
                    const int v = mt * 16 + rrow + rr;
                    if (v < V) {
                        float val = acc[mt][ni][rr] + bb
                                  + tl_table[sTL[v] * C + c] + lane_table[sLT[v] * C + c];
                        s1[c * 72 + v] = f2bf(val);
                    }
                }
        }
    }
    // wave-local chain: phase A wrote rows 32*wid..+31 of s1; phase B reads the same stripe.

    // ==== Phase B: expand fc1 (K=32 padded), in-place gelu into s1[c*72 + t]
    {
        bf16x8 af[2];
#pragma unroll
        for (int mt = 0; mt < 2; ++mt) {
            const int m = 32 * wid + mt * 16 + lrow;
            af[mt] = *(const bf16x8*)(s1 + m * 72 + kq);
        }
        floatx4 acc[2][4];
#pragma unroll
        for (int mt = 0; mt < 2; ++mt)
#pragma unroll
            for (int nt = 0; nt < 4; ++nt) acc[mt][nt] = {0.f, 0.f, 0.f, 0.f};
        const unsigned short* wB = ws + WS_TOKFC1;
#pragma unroll
        for (int nt = 0; nt < 4; ++nt) {
            const int n = nt * 16 + lrow;
            bf16x8 b = *(const bf16x8*)(wB + n * 32 + kq);
            acc[0][nt] = mfma16(af[0], b, acc[0][nt]);
            acc[1][nt] = mfma16(af[1], b, acc[1][nt]);
        }
#pragma unroll
        for (int nt = 0; nt < 4; ++nt) {
            const int t = nt * 16 + lrow;
            const float bb = tok_fc1_b[t];
#pragma unroll
            for (int mt = 0; mt < 2; ++mt)
#pragma unroll
                for (int rr = 0; rr < 4; ++rr) {
                    const int m = 32 * wid + mt * 16 + rrow + rr;
                    s1[m * 72 + t] = f2bf(gelu(acc[mt][nt][rr] + bb));
                }
        }
    }
    __syncthreads();   // phase C reads s1 rows across all waves

    // ==== residual in registers (8 floatx4 = 32 fp32) ====
    floatx4 R[8];
#pragma unroll
    for (int nt = 0; nt < 8; ++nt) R[nt] = {0.f, 0.f, 0.f, 0.f};

    // Phase C: expand fc2 (K=64), swapped orientation -> R directly
    tok_fc2_to_R(s1, ws + WS_TOKFC2, tok_fc2_b, R, wid, lrow, kq, rrow);

    // ==== Mixer blocks ====
#pragma unroll 1
    for (int blk = 0; blk < DEPTH; ++blk) {
        __syncthreads();   // prior cross-wave s1 reads done before ln1 overwrites
        ln_reg(R, bn1w + blk * C, bn1b + blk * C, s1, wid, lrow, rrow, true);
        __syncthreads();   // ln1 writes (all threads scatter) visible
        tok_fc1_gelu(s1, ws + WS_BTOK1 + blk * 4096, btok1b + blk * T, wid, lrow, kq, rrow);
        __syncthreads();   // tok_fc1 wave-local writes visible (tok_fc2 reads all rows)
        tok_fc2_to_R(s1, ws + WS_BTOK2 + blk * 4096, btok2b + blk * T, R, wid, lrow, kq, rrow);
        __syncthreads();   // tok_fc2 cross-wave reads done before ln2 overwrites
        ln_reg(R, bn2w + blk * C, bn2b + blk * C, s1, wid, lrow, rrow, false);
        // ln2 writes rows [16w,16w+16) (wave-local); ch chain stays wave-local:
        ch_fc1_gelu(s1, ws + WS_BCH1 + blk * 16384, bch1b + blk * C, wid, lrow, kq, rrow);
        ch_fc2_to_R(s1, ws + WS_BCH2 + blk * 16384, bch2b + blk * C, R, wid, lrow, kq, rrow);
    }
    __syncthreads();   // all ch_fc2 reads done before s1 reuse as pool buffer

    // ==== mean over tokens (from R) + final LN + head ====
    {
        float* P = (float*)s1;               // [4][128] fp32 partials
        float snt[8];
#pragma unroll
        for (int nt = 0; nt < 8; ++nt)
            snt[nt] = (R[nt][0] + R[nt][1]) + (R[nt][2] + R[nt][3]);
#pragma unroll
        for (int nt = 0; nt < 8; ++nt) {
            snt[nt] += __shfl_xor(snt[nt], 16);
            snt[nt] += __shfl_xor(snt[nt], 32);
        }
        if (lane < 16) {
#pragma unroll
            for (int nt = 0; nt < 8; ++nt)
                P[wid * 128 + 16 * nt + lane] = snt[nt];
        }
    }
    __syncthreads();
    float fm = 0.f;
    {
        const float* P = (const float*)s1;
        if (tid < C) {
            fm = (P[tid] + P[128 + tid] + P[256 + tid] + P[384 + tid]) * (1.f / 64.f);
            sVec[tid] = fm;
        }
    }
    __syncthreads();
    {
        float s = 0.f, q = 0.f;
#pragma unroll
        for (int c = 0; c < C; c += 4) {
            float4 v = *(const float4*)(sVec + c);
            s += (v.x + v.y) + (v.z + v.w);
            q += v.x * v.x + v.y * v.y + v.z * v.z + v.w * v.w;
        }
        __syncthreads();
        const float m = s * (1.f / 128.f);
        const float rs = rsqrtf(q * (1.f / 128.f) - m * m + 1e-5f);
        if (tid < C) sVec[tid] = (fm - m) * rs * norm_w[tid] + norm_b[tid];
    }
    __syncthreads();

    if (tid < HDIM) {
        float a0 = 0.f, a1 = 0.f, a2 = 0.f, a3 = 0.f;
#pragma unroll 8
        for (int c = 0; c < C; c += 4) {
            float4 sv = *(const float4*)(sVec + c);
            a0 = fmaf(sv.x, emb1w[(c + 0) * HDIM + tid], a0);
            a1 = fmaf(sv.y, emb1w[(c + 1) * HDIM + tid], a1);
            a2 = fmaf(sv.z, emb1w[(c + 2) * HDIM + tid], a2);
            a3 = fmaf(sv.w, emb1w[(c + 3) * HDIM + tid], a3);
        }
        sVec[C + tid] = gelu(((a0 + a1) + (a2 + a3)) + emb1b[tid]);
    }
    __syncthreads();
    if (tid < HDIM) {
        float a0 = 0.f, a1 = 0.f, a2 = 0.f, a3 = 0.f;
#pragma unroll 8
        for (int j = 0; j < HDIM; j += 4) {
            float4 sv = *(const float4*)(sVec + C + j);
            a0 = fmaf(sv.x, emb2w[(j + 0) * HDIM + tid], a0);
            a1 = fmaf(sv.y, emb2w[(j + 1) * HDIM + tid], a1);
            a2 = fmaf(sv.z, emb2w[(j + 2) * HDIM + tid], a2);
            a3 = fmaf(sv.w, emb2w[(j + 3) * HDIM + tid], a3);
        }
        outp[(size_t)r * HDIM + tid] = (((a0 + a1) + (a2 + a3)) + emb2b[tid]) * sValidF;
    }
}

// ================= fallback scalar kernel (R1 version) =================
template<int K, int LDA, int N>
__device__ __forceinline__ void gemm_bf(const unsigned short* __restrict__ A,
                                        const float* __restrict__ W,
                                        float acc[4][8])
{
#pragma unroll 2
    for (int k = 0; k < K; k += 4) {
        float a[4][4];
#pragma unroll
        for (int i = 0; i < 4; ++i) {
            ushort4 raw = *(const ushort4*)(A + i * LDA + k);
            a[i][0] = bf2f(raw.x); a[i][1] = bf2f(raw.y);
            a[i][2] = bf2f(raw.z); a[i][3] = bf2f(raw.w);
        }
#pragma unroll
        for (int kk = 0; kk < 4; ++kk) {
            const float* wr = W + (k + kk) * N;
            float4 w0 = *(const float4*)(wr);
            float4 w1 = *(const float4*)(wr + 4);
#pragma unroll
            for (int i = 0; i < 4; ++i) {
                acc[i][0] = fmaf(a[i][kk], w0.x, acc[i][0]);
                acc[i][1] = fmaf(a[i][kk], w0.y, acc[i][1]);
                acc[i][2] = fmaf(a[i][kk], w0.z, acc[i][2]);
                acc[i][3] = fmaf(a[i][kk], w0.w, acc[i][3]);
                acc[i][4] = fmaf(a[i][kk], w1.x, acc[i][4]);
                acc[i][5] = fmaf(a[i][kk], w1.y, acc[i][5]);
                acc[i][6] = fmaf(a[i][kk], w1.z, acc[i][6]);
                acc[i][7] = fmaf(a[i][kk], w1.w, acc[i][7]);
            }
        }
    }
}

template<int K, int LDA, int N>
__device__ __forceinline__ void gemm_f32(const float* __restrict__ A,
                                         const float* __restrict__ W,
                                         float acc[4][8])
{
#pragma unroll
    for (int k = 0; k < K; k += 4) {
        float a[4][4];
#pragma unroll
        for (int i = 0; i < 4; ++i) {
            float4 v = *(const float4*)(A + i * LDA + k);
            a[i][0] = v.x; a[i][1] = v.y; a[i][2] = v.z; a[i][3] = v.w;
        }
#pragma unroll
        for (int kk = 0; kk < 4; ++kk) {
            const float* wr = W + (k + kk) * N;
            float4 w0 = *(const float4*)(wr);
            float4 w1 = *(const float4*)(wr + 4);
#pragma unroll
            for (int i = 0; i < 4; ++i) {
                acc[i][0] = fmaf(a[i][kk], w0.x, acc[i][0]);
                acc[i][1] = fmaf(a[i][kk], w0.y, acc[i][1]);
                acc[i][2] = fmaf(a[i][kk], w0.z, acc[i][2]);
                acc[i][3] = fmaf(a[i][kk], w0.w, acc[i][3]);
                acc[i][4] = fmaf(a[i][kk], w1.x, acc[i][4]);
                acc[i][5] = fmaf(a[i][kk], w1.y, acc[i][5]);
                acc[i][6] = fmaf(a[i][kk], w1.z, acc[i][6]);
                acc[i][7] = fmaf(a[i][kk], w1.w, acc[i][7]);
            }
        }
    }
}

__global__ __launch_bounds__(256, 3)
void lanefusion_scalar(
    const float* __restrict__ x,
    const float* __restrict__ tl_table, const float* __restrict__ lane_table,
    const float* __restrict__ ch_fc1_w, const float* __restrict__ ch_fc1_b,
    const float* __restrict__ ch_fc2_w, const float* __restrict__ ch_fc2_b,
    const float* __restrict__ tok_fc1_w, const float* __restrict__ tok_fc1_b,
    const float* __restrict__ tok_fc2_w, const float* __restrict__ tok_fc2_b,
    const float* __restrict__ bn1w, const float* __restrict__ bn1b,
    const float* __restrict__ btok1w, const float* __restrict__ btok1b,
    const float* __restrict__ btok2w, const float* __restrict__ btok2b,
    const float* __restrict__ bn2w, const float* __restrict__ bn2b,
    const float* __restrict__ bch1w, const float* __restrict__ bch1b,
    const float* __restrict__ bch2w, const float* __restrict__ bch2b,
    const float* __restrict__ norm_w, const float* __restrict__ norm_b,
    const float* __restrict__ emb1w, const float* __restrict__ emb1b,
    const float* __restrict__ emb2w, const float* __restrict__ emb2b,
    float* __restrict__ out)
{
    __shared__ float sF[T * 132];
    __shared__ unsigned short sA[8704];
    __shared__ float sVec[320];
    __shared__ int sTL[V], sLT[V], sMaskV[V];
    __shared__ float sValidF;

    const int tid = threadIdx.x;
    const int r = blockIdx.x;

    float* outp  = out;
    float* maskp = out + (size_t)NROWS * HDIM;
    float* posp  = maskp + NROWS;

    float* sX = sVec;
    float* sG = sVec + 128;

    const float* xr = x + (size_t)r * (V * 5);
    if (tid < V * 5) sX[tid] = xr[tid];
    __syncthreads();

    if (tid < V) {
        float x0 = sX[tid * 5 + 0], x1 = sX[tid * 5 + 1], hd = sX[tid * 5 + 2];
        float chv = cosf(hd), shv = sinf(hd);
        sG[tid * 4 + 0] = x0; sG[tid * 4 + 1] = x1;
        sG[tid * 4 + 2] = chv; sG[tid * 4 + 3] = shv;
        int nz = (x0 != 0.f) + (x1 != 0.f) + (chv != 0.f) + (shv != 0.f);
        sMaskV[tid] = (nz == 0);
        int tl = (int)sX[tid * 5 + 3]; tl = tl < 0 ? 0 : (tl > 8 ? 8 : tl);
        int lt = (int)sX[tid * 5 + 4]; lt = lt < 0 ? 0 : (lt > 19 ? 19 : lt);
        sTL[tid] = tl; sLT[tid] = lt;
    }
    __syncthreads();

    if (tid == 0) {
        int mp = 1;
        for (int v = 0; v < V; ++v) mp &= sMaskV[v];
        sValidF = mp ? 0.f : 1.f;
        maskp[r] = mp ? 1.f : 0.f;
        posp[(size_t)r * 5 + 0] = sX[50];
        posp[(size_t)r * 5 + 1] = sX[51];
        posp[(size_t)r * 5 + 2] = sX[52];
        posp[(size_t)r * 5 + 3] = sX[53] * (1.f / 8.f);
        posp[(size_t)r * 5 + 4] = sX[54] * (1.f / 19.f);
    }

    if (tid < 160) {
        const int v = tid >> 3, c0 = (tid & 7) * 16;
        const float g0 = sG[v * 4 + 0], g1 = sG[v * 4 + 1],
                    g2 = sG[v * 4 + 2], g3 = sG[v * 4 + 3];
#pragma unroll
        for (int j = 0; j < 16; ++j) {
            const int c = c0 + j;
            float s = ch_fc1_b[c];
            s = fmaf(g0, ch_fc1_w[0 * C + c], s);
            s = fmaf(g1, ch_fc1_w[1 * C + c], s);
            s = fmaf(g2, ch_fc1_w[2 * C + c], s);
            s = fmaf(g3, ch_fc1_w[3 * C + c], s);
            sA[v * 132 + c] = f2bf(gelu(s));
        }
    }
    __syncthreads();

    if (tid < 160) {
        const int v = tid >> 3, c0 = (tid & 7) * 16;
        float acc[16];
#pragma unroll
        for (int j = 0; j < 16; ++j) acc[j] = 0.f;
        const unsigned short* Arow = sA + v * 132;
        for (int k = 0; k < C; k += 4) {
            ushort4 raw = *(const ushort4*)(Arow + k);
            float a4[4] = { bf2f(raw.x), bf2f(raw.y), bf2f(raw.z), bf2f(raw.w) };
#pragma unroll
            for (int kk = 0; kk < 4; ++kk) {
                const float* wr = ch_fc2_w + (k + kk) * C + c0;
                float4 w0 = *(const float4*)(wr);
                float4 w1 = *(const float4*)(wr + 4);
                float4 w2 = *(const float4*)(wr + 8);
                float4 w3 = *(const float4*)(wr + 12);
                acc[0]  = fmaf(a4[kk], w0.x, acc[0]);  acc[1]  = fmaf(a4[kk], w0.y, acc[1]);
                acc[2]  = fmaf(a4[kk], w0.z, acc[2]);  acc[3]  = fmaf(a4[kk], w0.w, acc[3]);
                acc[4]  = fmaf(a4[kk], w1.x, acc[4]);  acc[5]  = fmaf(a4[kk], w1.y, acc[5]);
                acc[6]  = fmaf(a4[kk], w1.z, acc[6]);  acc[7]  = fmaf(a4[kk], w1.w, acc[7]);
                acc[8]  = fmaf(a4[kk], w2.x, acc[8]);  acc[9]  = fmaf(a4[kk], w2.y, acc[9]);
                acc[10] = fmaf(a4[kk], w2.z, acc[10]); acc[11] = fmaf(a4[kk], w2.w, acc[11]);
                acc[12] = fmaf(a4[kk], w3.x, acc[12]); acc[13] = fmaf(a4[kk], w3.y, acc[13]);
                acc[14] = fmaf(a4[kk], w3.z, acc[14]); acc[15] = fmaf(a4[kk], w3.w, acc[15]);
            }
        }
        const int tl = sTL[v], lt = sLT[v];
#pragma unroll
        for (int j = 0; j < 16; ++j) {
            const int c = c0 + j;
            sF[c * 20 + v] = acc[j] + ch_fc2_b[c] + tl_table[tl * C + c] + lane_table[lt * C + c];
        }
    }
    __syncthreads();

    {
        const int r0 = (tid >> 3) * 4, c0 = (tid & 7) * 8;
        float acc[4][8] = {};
        gemm_f32<20, 20, 64>(sF + r0 * 20, tok_fc1_w + c0, acc);
#pragma unroll
        for (int i = 0; i < 4; ++i)
#pragma unroll
            for (int j = 0; j < 8; ++j)
                sA[(r0 + i) * 68 + c0 + j] = f2bf(gelu(acc[i][j] + tok_fc1_b[c0 + j]));
    }
    __syncthreads();

    {
        const int r0 = (tid >> 3) * 4, c0 = (tid & 7) * 8;
        float acc[4][8] = {};
        gemm_bf<64, 68, 64>(sA + r0 * 68, tok_fc2_w + c0, acc);
#pragma unroll
        for (int i = 0; i < 4; ++i)
#pragma unroll
            for (int j = 0; j < 8; ++j)
                sF[(c0 + j) * 132 + (r0 + i)] = acc[i][j] + tok_fc2_b[c0 + j];
    }
    __syncthreads();

    for (int blk = 0; blk < DEPTH; ++blk) {
        layer_norm_to(sF, sA, bn1w + blk * C, bn1b + blk * C, tid, true, 68);
        __syncthreads();
        {
            const int r0 = (tid >> 3) * 4, c0 = (tid & 7) * 8;
            float acc[4][8] = {};
            gemm_bf<64, 68, 64>(sA + r0 * 68, btok1w + blk * T * T + c0, acc);
#pragma unroll
            for (int i = 0; i < 4; ++i)
#pragma unroll
                for (int j = 0; j < 8; ++j)
                    acc[i][j] = gelu(acc[i][j] + btok1b[blk * T + c0 + j]);
            __syncthreads();
#pragma unroll
            for (int i = 0; i < 4; ++i)
#pragma unroll
                for (int j = 0; j < 8; ++j)
                    sA[(r0 + i) * 68 + c0 + j] = f2bf(acc[i][j]);
        }
        __syncthreads();
        {
            const int r0 = (tid >> 3) * 4, c0 = (tid & 7) * 8;
            float acc[4][8] = {};
            gemm_bf<64, 68, 64>(sA + r0 * 68, btok2w + blk * T * T + c0, acc);
#pragma unroll
            for (int i = 0; i < 4; ++i)
#pragma unroll
                for (int j = 0; j < 8; ++j)
                    sF[(c0 + j) * 132 + (r0 + i)] += acc[i][j] + btok2b[blk * T + c0 + j];
        }
        __syncthreads();

        layer_norm_to(sF, sA, bn2w + blk * C, bn2b + blk * C, tid, false, 132);
        __syncthreads();
        {
            const int r0 = (tid >> 4) * 4, c0 = (tid & 15) * 8;
            float acc[4][8] = {};
            gemm_bf<128, 132, 128>(sA + r0 * 132, bch1w + blk * C * C + c0, acc);
#pragma unroll
            for (int i = 0; i < 4; ++i)
#pragma unroll
                for (int j = 0; j < 8; ++j)
                    acc[i][j] = gelu(acc[i][j] + bch1b[blk * C + c0 + j]);
            __syncthreads();
#pragma unroll
            for (int i = 0; i < 4; ++i)
#pragma unroll
                for (int j = 0; j < 8; ++j)
                    sA[(r0 + i) * 132 + c0 + j] = f2bf(acc[i][j]);
        }
        __syncthreads();
        {
            const int r0 = (tid >> 4) * 4, c0 = (tid & 15) * 8;
            float acc[4][8] = {};
            gemm_bf<128, 132, 128>(sA + r0 * 132, bch2w + blk * C * C + c0, acc);
#pragma unroll
            for (int i = 0; i < 4; ++i)
#pragma unroll
                for (int j = 0; j < 8; ++j)
                    sF[(r0 + i) * 132 + c0 + j] += acc[i][j] + bch2b[blk * C + c0 + j];
        }
        __syncthreads();
    }

    float fm = 0.f;
    if (tid < C) {
#pragma unroll 8
        for (int t = 0; t < T; ++t) fm += sF[t * 132 + tid];
        fm *= (1.f / 64.f);
        sVec[tid] = fm;
    }
    __syncthreads();
    {
        float s = 0.f, q = 0.f;
        for (int c = 0; c < C; ++c) { float v = sVec[c]; s += v; q += v * v; }
        __syncthreads();
        const float m = s * (1.f / 128.f);
        const float rs = rsqrtf(q * (1.f / 128.f) - m * m + 1e-5f);
        if (tid < C) sVec[tid] = (fm - m) * rs * norm_w[tid] + norm_b[tid];
    }
    __syncthreads();

    if (tid < HDIM) {
        float v1 = emb1b[tid];
        for (int c = 0; c < C; ++c) v1 = fmaf(sVec[c], emb1w[c * HDIM + tid], v1);
        sVec[C + tid] = gelu(v1);
    }
    __syncthreads();
    if (tid < HDIM) {
        float v2 = emb2b[tid];
        for (int j = 0; j < HDIM; ++j) v2 = fmaf(sVec[C + j], emb2w[j * HDIM + tid], v2);
        outp[(size_t)r * HDIM + tid] = v2 * sValidF;
    }
}

extern "C" void kernel_launch(void* const* d_in, const int* in_sizes, int n_in,
                              void* d_out, int out_size, void* d_ws, size_t ws_size,
                              hipStream_t stream) {
    (void)in_sizes; (void)n_in; (void)out_size;
    if (ws_size >= (size_t)WS_TOTAL * 2) {
        prep_weights<<<dim3((WS_TOTAL + 255) / 256), dim3(256), 0, stream>>>(
            (const float*)d_in[7],  // tok_fc1_w
            (const float*)d_in[9],  // tok_fc2_w
            (const float*)d_in[13], // blk_tok_fc1_w
            (const float*)d_in[15], // blk_tok_fc2_w
            (const float*)d_in[5],  // ch_fc2_w
            (const float*)d_in[19], // blk_ch_fc1_w
            (const float*)d_in[21], // blk_ch_fc2_w
            (unsigned short*)d_ws);
        lanefusion_mfma<<<dim3(NROWS), dim3(256), 0, stream>>>(
            (const float*)d_in[0],  (const float*)d_in[1],  (const float*)d_in[2],
            (const float*)d_in[3],  (const float*)d_in[4],
            (const float*)d_in[6],
            (const float*)d_in[8],  (const float*)d_in[10],
            (const float*)d_in[11], (const float*)d_in[12],
            (const float*)d_in[14], (const float*)d_in[16],
            (const float*)d_in[17], (const float*)d_in[18],
            (const float*)d_in[20], (const float*)d_in[22],
            (const float*)d_in[23], (const float*)d_in[24],
            (const float*)d_in[25], (const float*)d_in[26],
            (const float*)d_in[27], (const float*)d_in[28],
            (const unsigned short*)d_ws,
            (float*)d_out);
    } else {
        lanefusion_scalar<<<dim3(NROWS), dim3(256), 0, stream>>>(
            (const float*)d_in[0],  (const float*)d_in[1],  (const float*)d_in[2],
            (const float*)d_in[3],  (const float*)d_in[4],  (const float*)d_in[5],
            (const float*)d_in[6],  (const float*)d_in[7],  (const float*)d_in[8],
            (const float*)d_in[9],  (const float*)d_in[10], (const float*)d_in[11],
            (const float*)d_in[12], (const float*)d_in[13], (const float*)d_in[14],
            (const float*)d_in[15], (const float*)d_in[16], (const float*)d_in[17],
            (const float*)d_in[18], (const float*)d_in[19], (const float*)d_in[20],
            (const float*)d_in[21], (const float*)d_in[22], (const float*)d_in[23],
            (const float*)d_in[24], (const float*)d_in[25], (const float*)d_in[26],
            (const float*)d_in[27], (const float*)d_in[28],
            (float*)d_out);
    }
}